// Round 1
// baseline (382.301 us; speedup 1.0000x reference)
//
#include <hip/hip_runtime.h>
#include <hip/hip_bf16.h>
#include <stdint.h>

// MultiHeadAttention: out = ((q@WqT).reshape -> per-token head-axis attention -> ) @ WoT
// B=4 S=4096 D=1024 H=16 DH=64. Attention is per-token 16x16 over head axis.
// Round 1: bf16-MFMA GEMMs (reg-staged f32->bf16 conversion), wave-per-token attention.

namespace {
constexpr int kD  = 1024;
constexpr int kH  = 16;
constexpr int kDH = 64;
constexpr int kM  = 4 * 4096;   // 16384 tokens

constexpr int BM = 128, BN = 128, BK = 32;
constexpr int LDSP = BK + 8;    // 40 shorts/row = 80B stride -> ~2-way max bank conflict (free)

typedef __attribute__((ext_vector_type(4))) float f32x4;
typedef __attribute__((ext_vector_type(8))) short s16x8;

__device__ __forceinline__ unsigned short f2b(float f) {
  uint32_t x = __builtin_bit_cast(uint32_t, f);
  x += 0x7fffu + ((x >> 16) & 1u);   // round-to-nearest-even
  return (unsigned short)(x >> 16);
}
__device__ __forceinline__ float b2f(unsigned short u) {
  return __builtin_bit_cast(float, (uint32_t)u << 16);
}

// 16 consecutive f32 (global) -> 16 bf16 -> two 16B LDS writes
__device__ __forceinline__ void cvt16_store(const float* __restrict__ g, short* __restrict__ l) {
  const f32x4* s4 = (const f32x4*)g;
  f32x4 f0 = s4[0], f1 = s4[1], f2 = s4[2], f3 = s4[3];
  s16x8 o0, o1;
#pragma unroll
  for (int i = 0; i < 4; ++i) {
    o0[i]     = (short)f2b(f0[i]);
    o0[4 + i] = (short)f2b(f1[i]);
    o1[i]     = (short)f2b(f2[i]);
    o1[4 + i] = (short)f2b(f3[i]);
  }
  *(s16x8*)l = o0;
  *(s16x8*)(l + 8) = o1;
}

// C[m,n] = sum_k A[m,k] * W[n,k]  (x @ W.T), A: kM x kD, W: kD x kD
template <bool A_BF16, bool OUT_F32>
__device__ __forceinline__ void gemm_body(const void* __restrict__ Ap,
                                          const float* __restrict__ Wp,
                                          void* __restrict__ Cp) {
  constexpr int N = kD, K = kD;
  __shared__ short As[BM * LDSP];
  __shared__ short Bs[BN * LDSP];

  const int t  = threadIdx.x;
  const int m0 = blockIdx.y * BM;
  const int n0 = blockIdx.x * BN;

  const int srow = t >> 1;          // 0..127
  const int scol = (t & 1) * 16;    // 0 or 16

  const int lane = t & 63;
  const int wid  = t >> 6;
  const int wm   = (wid >> 1) * 64;
  const int wn   = (wid & 1) * 64;
  const int fr   = lane & 15;
  const int fk   = (lane >> 4) * 8;

  f32x4 acc[4][4];
#pragma unroll
  for (int i = 0; i < 4; ++i)
#pragma unroll
    for (int j = 0; j < 4; ++j) acc[i][j] = (f32x4){0.f, 0.f, 0.f, 0.f};

  for (int k0 = 0; k0 < K; k0 += BK) {
    if constexpr (A_BF16) {
      const unsigned short* Ab = (const unsigned short*)Ap;
      const s16x8* src = (const s16x8*)(Ab + (size_t)(m0 + srow) * K + k0 + scol);
      s16x8 v0 = src[0], v1 = src[1];
      *(s16x8*)(As + srow * LDSP + scol) = v0;
      *(s16x8*)(As + srow * LDSP + scol + 8) = v1;
    } else {
      cvt16_store((const float*)Ap + (size_t)(m0 + srow) * K + k0 + scol,
                  As + srow * LDSP + scol);
    }
    cvt16_store(Wp + (size_t)(n0 + srow) * K + k0 + scol,
                Bs + srow * LDSP + scol);
    __syncthreads();

    s16x8 af[4], bw[4];
#pragma unroll
    for (int i = 0; i < 4; ++i)
      af[i] = *(const s16x8*)(As + (wm + i * 16 + fr) * LDSP + fk);
#pragma unroll
    for (int j = 0; j < 4; ++j)
      bw[j] = *(const s16x8*)(Bs + (wn + j * 16 + fr) * LDSP + fk);
#pragma unroll
    for (int i = 0; i < 4; ++i)
#pragma unroll
      for (int j = 0; j < 4; ++j)
        acc[i][j] = __builtin_amdgcn_mfma_f32_16x16x32_bf16(af[i], bw[j], acc[i][j], 0, 0, 0);
    __syncthreads();
  }

  // C/D layout: col = lane&15, row = (lane>>4)*4 + r   [measured m89/m91]
  const int cr = (lane >> 4) * 4;
  const int cc = lane & 15;
#pragma unroll
  for (int i = 0; i < 4; ++i)
#pragma unroll
    for (int j = 0; j < 4; ++j)
#pragma unroll
      for (int r = 0; r < 4; ++r) {
        size_t row = (size_t)(m0 + wm + i * 16 + cr + r);
        size_t col = (size_t)(n0 + wn + j * 16 + cc);
        if constexpr (OUT_F32)
          ((float*)Cp)[row * N + col] = acc[i][j][r];
        else
          ((unsigned short*)Cp)[row * N + col] = f2b(acc[i][j][r]);
      }
}

__global__ __launch_bounds__(256) void proj_gemm(
    const float* __restrict__ q, const float* __restrict__ k, const float* __restrict__ v,
    const float* __restrict__ Wq, const float* __restrict__ Wk, const float* __restrict__ Wv,
    unsigned short* __restrict__ qh, unsigned short* __restrict__ kh,
    unsigned short* __restrict__ vh) {
  const float* A;
  const float* W;
  unsigned short* C;
  if (blockIdx.z == 0)      { A = q; W = Wq; C = qh; }
  else if (blockIdx.z == 1) { A = k; W = Wk; C = kh; }
  else                      { A = v; W = Wv; C = vh; }
  gemm_body<false, false>(A, W, C);
}

__global__ __launch_bounds__(256) void out_gemm(const unsigned short* __restrict__ attn,
                                                const float* __restrict__ Wo,
                                                float* __restrict__ out) {
  gemm_body<true, true>(attn, Wo, out);
}

// One wave per token: S = (qh·khT)/8 * mask, row-softmax over head axis, attn = P·vh
__global__ __launch_bounds__(256) void attn_tok(const unsigned short* __restrict__ qh,
                                                const unsigned short* __restrict__ kh,
                                                const unsigned short* __restrict__ vh,
                                                const float* __restrict__ mask,
                                                unsigned short* __restrict__ attn) {
  __shared__ float P[4][16][17];
  __shared__ unsigned short Vs[4][16 * 64];
  const int lane = threadIdx.x & 63;
  const int wid  = threadIdx.x >> 6;
  const size_t tok = (size_t)blockIdx.x * 4 + wid;

  const unsigned short* qp = qh + tok * kD;
  const unsigned short* kp = kh + tok * kD;
  const unsigned short* vp = vh + tok * kD;

  // stage V (2KB) into LDS: 32B per lane
  {
    const s16x8* src = (const s16x8*)vp;
    s16x8 a = src[2 * lane], b = src[2 * lane + 1];
    s16x8* dst = (s16x8*)Vs[wid];
    dst[2 * lane] = a;
    dst[2 * lane + 1] = b;
  }

  // QK^T via two 16x16x32 MFMAs (K = DH = 64)
  const int fr = lane & 15;
  const int fk = (lane >> 4) * 8;
  s16x8 a0 = *(const s16x8*)(qp + fr * kDH + fk);
  s16x8 a1 = *(const s16x8*)(qp + fr * kDH + 32 + fk);
  s16x8 b0 = *(const s16x8*)(kp + fr * kDH + fk);
  s16x8 b1 = *(const s16x8*)(kp + fr * kDH + 32 + fk);
  f32x4 s = {0.f, 0.f, 0.f, 0.f};
  s = __builtin_amdgcn_mfma_f32_16x16x32_bf16(a0, b0, s, 0, 0, 0);
  s = __builtin_amdgcn_mfma_f32_16x16x32_bf16(a1, b1, s, 0, 0, 0);

  // scale + multiplicative mask + row softmax (row h spread over lanes 0..15 of each group)
  const int cr = (lane >> 4) * 4;
  const int cc = lane & 15;
  float p[4];
#pragma unroll
  for (int r = 0; r < 4; ++r) {
    float val = s[r] * 0.125f * mask[(cr + r) * kH + cc];
    float mx = val;
#pragma unroll
    for (int d = 1; d < 16; d <<= 1) mx = fmaxf(mx, __shfl_xor(mx, d));
    float e = __expf(val - mx);
    float sum = e;
#pragma unroll
    for (int d = 1; d < 16; d <<= 1) sum += __shfl_xor(sum, d);
    p[r] = e / sum;
  }
#pragma unroll
  for (int r = 0; r < 4; ++r) P[wid][cr + r][cc] = p[r];

  // attn[h][d0..d0+15] = sum_g P[h][g] * V[g][d]   (lane: h = lane>>2, d-quarter = lane&3)
  const int h  = lane >> 2;
  const int d0 = (lane & 3) * 16;
  float o[16];
#pragma unroll
  for (int i = 0; i < 16; ++i) o[i] = 0.f;
#pragma unroll
  for (int g = 0; g < 16; ++g) {
    float pg = P[wid][h][g];
    s16x8 v0 = *(const s16x8*)(Vs[wid] + g * kDH + d0);
    s16x8 v1 = *(const s16x8*)(Vs[wid] + g * kDH + d0 + 8);
#pragma unroll
    for (int dd = 0; dd < 8; ++dd) {
      o[dd]     += pg * b2f((unsigned short)v0[dd]);
      o[8 + dd] += pg * b2f((unsigned short)v1[dd]);
    }
  }
  unsigned short* op = attn + tok * kD + h * kDH + d0;
  s16x8 r0, r1;
#pragma unroll
  for (int dd = 0; dd < 8; ++dd) {
    r0[dd] = (short)f2b(o[dd]);
    r1[dd] = (short)f2b(o[dd + 8]);
  }
  *(s16x8*)op = r0;
  *(s16x8*)(op + 8) = r1;
}

}  // namespace

extern "C" void kernel_launch(void* const* d_in, const int* in_sizes, int n_in,
                              void* d_out, int out_size, void* d_ws, size_t ws_size,
                              hipStream_t stream) {
  (void)in_sizes; (void)n_in; (void)out_size;
  const float* q    = (const float*)d_in[0];
  const float* k    = (const float*)d_in[1];
  const float* v    = (const float*)d_in[2];
  const float* mask = (const float*)d_in[3];
  const float* Wq   = (const float*)d_in[4];
  const float* Wk   = (const float*)d_in[5];
  const float* Wv   = (const float*)d_in[6];
  const float* Wo   = (const float*)d_in[7];

  const size_t per = (size_t)kM * kD;  // 16.7M elements per bf16 buffer
  unsigned short* qh = (unsigned short*)d_ws;
  unsigned short* kh = qh + per;
  unsigned short* vh = kh + per;
  // If ws is tight, alias attn onto qh: safe — attention reads token t's q-row
  // (start of wave) strictly before writing token t's attn row (end of wave),
  // rows are disjoint across tokens, and out_gemm is stream-ordered after.
  unsigned short* at = (ws_size >= 4 * per * sizeof(unsigned short)) ? (vh + per) : qh;

  proj_gemm<<<dim3(kD / BN, kM / BM, 3), 256, 0, stream>>>(q, k, v, Wq, Wk, Wv, qh, kh, vh);
  attn_tok<<<dim3(kM / 4), 256, 0, stream>>>(qh, kh, vh, mask, at);
  out_gemm<<<dim3(kD / BN, kM / BM), 256, 0, stream>>>(at, Wo, (float*)d_out);
}

// Round 2
// 284.146 us; speedup vs baseline: 1.3454x; 1.3454x over previous
//
#include <hip/hip_runtime.h>
#include <hip/hip_bf16.h>
#include <stdint.h>

// MultiHeadAttention: B=4 S=4096 D=1024 H=16 DH=64; attention is per-token 16x16
// over the head axis. Round 2: one f32->bf16 convert pass, then m97-structure
// bf16 GEMMs (global_load_lds width-16, linear LDS, 2-barrier K-loop).

namespace {
constexpr int kD  = 1024;
constexpr int kH  = 16;
constexpr int kDH = 64;
constexpr int kM  = 4 * 4096;             // 16384 tokens
constexpr size_t PER = (size_t)kM * kD;   // 16.78M elems (q/k/v-sized)
constexpr size_t WSZ = (size_t)kD * kD;   // 1.05M elems (weight-sized)

constexpr int BM = 128, BN = 128, BK = 32;

typedef __attribute__((ext_vector_type(4))) float f32x4;
typedef __attribute__((ext_vector_type(8))) short s16x8;

__device__ __forceinline__ unsigned short f2b(float f) {
  uint32_t x = __builtin_bit_cast(uint32_t, f);
  x += 0x7fffu + ((x >> 16) & 1u);   // round-to-nearest-even
  return (unsigned short)(x >> 16);
}
__device__ __forceinline__ float b2f(unsigned short u) {
  return __builtin_bit_cast(float, (uint32_t)u << 16);
}

typedef __attribute__((address_space(3))) void as3_void;
typedef __attribute__((address_space(1))) void as1_void;
__device__ __forceinline__ void gload_lds16(const void* g, void* l) {
  // LDS dest is wave-uniform base + lane*16 (HW adds the lane offset).
  __builtin_amdgcn_global_load_lds((const as1_void*)(uintptr_t)g,
                                   (as3_void*)(uint32_t)(uintptr_t)l, 16, 0, 0);
}

// ---------------- convert pass: 7 f32 tensors -> consecutive bf16 buffers ----
__global__ __launch_bounds__(256) void cvt_bf16(
    const float* __restrict__ q, const float* __restrict__ k, const float* __restrict__ v,
    const float* __restrict__ Wq, const float* __restrict__ Wk, const float* __restrict__ Wv,
    const float* __restrict__ Wo, unsigned short* __restrict__ out) {
  const size_t total8 = (3 * PER + 4 * WSZ) / 8;
  for (size_t i8 = (size_t)blockIdx.x * blockDim.x + threadIdx.x; i8 < total8;
       i8 += (size_t)gridDim.x * blockDim.x) {
    size_t i = i8 * 8;
    const float* s; size_t o;
    if (i < 3 * PER) {
      if (i < PER)            { s = q; o = i; }
      else if (i < 2 * PER)   { s = k; o = i - PER; }
      else                    { s = v; o = i - 2 * PER; }
    } else {
      size_t j = i - 3 * PER;
      if (j < WSZ)            { s = Wq; o = j; }
      else if (j < 2 * WSZ)   { s = Wk; o = j - WSZ; }
      else if (j < 3 * WSZ)   { s = Wv; o = j - 2 * WSZ; }
      else                    { s = Wo; o = j - 3 * WSZ; }
    }
    f32x4 f0 = ((const f32x4*)(s + o))[0];
    f32x4 f1 = ((const f32x4*)(s + o))[1];
    s16x8 r;
#pragma unroll
    for (int d = 0; d < 4; ++d) {
      r[d]     = (short)f2b(f0[d]);
      r[4 + d] = (short)f2b(f1[d]);
    }
    *(s16x8*)(out + i) = r;
  }
}

// ---------------- m97-structure bf16 GEMM: C[m,n] = sum_k A[m,k]*B[n,k] ------
template <bool OUT_F32>
__device__ __forceinline__ void gemm_lds_body(const unsigned short* __restrict__ A,
                                              const unsigned short* __restrict__ Bm,
                                              void* __restrict__ Cp) {
  constexpr int N = kD, K = kD;
  __shared__ __align__(16) unsigned short As[BM * BK];   // linear [128][32]
  __shared__ __align__(16) unsigned short Bs[BN * BK];

  const int t    = threadIdx.x;
  const int lane = t & 63;
  const int wv   = t >> 6;
  const int m0 = blockIdx.y * BM;
  const int n0 = blockIdx.x * BN;

  // staging geometry: wave wv owns rows [wv*32, wv*32+32), 2 issues of 16 rows
  const int r0 = wv * 32;
  const int rr = lane >> 2;         // 0..15 within a 16-row issue
  const int c8 = (lane & 3) * 8;    // bf16 col 0/8/16/24

  // fragment geometry: 2x2 wave grid, 4x4 16x16 frags per wave
  const int wm = (wv >> 1) * 64;
  const int wn = (wv & 1) * 64;
  const int fr = lane & 15;
  const int fk = (lane >> 4) * 8;

  f32x4 acc[4][4];
#pragma unroll
  for (int i = 0; i < 4; ++i)
#pragma unroll
    for (int j = 0; j < 4; ++j) acc[i][j] = (f32x4){0.f, 0.f, 0.f, 0.f};

  const unsigned short* gA = A  + (size_t)(m0 + r0 + rr) * K + c8;
  const unsigned short* gB = Bm + (size_t)(n0 + r0 + rr) * K + c8;

  for (int k0 = 0; k0 < K; k0 += BK) {
    gload_lds16(gA + k0,                  As + (r0 +  0) * BK);
    gload_lds16(gA + k0 + (size_t)16 * K, As + (r0 + 16) * BK);
    gload_lds16(gB + k0,                  Bs + (r0 +  0) * BK);
    gload_lds16(gB + k0 + (size_t)16 * K, Bs + (r0 + 16) * BK);
    __syncthreads();   // drains vmcnt before barrier

    s16x8 af[4], bw[4];
#pragma unroll
    for (int i = 0; i < 4; ++i)
      af[i] = *(const s16x8*)(As + (wm + i * 16 + fr) * BK + fk);
#pragma unroll
    for (int j = 0; j < 4; ++j)
      bw[j] = *(const s16x8*)(Bs + (wn + j * 16 + fr) * BK + fk);
#pragma unroll
    for (int i = 0; i < 4; ++i)
#pragma unroll
      for (int j = 0; j < 4; ++j)
        acc[i][j] = __builtin_amdgcn_mfma_f32_16x16x32_bf16(af[i], bw[j], acc[i][j], 0, 0, 0);
    __syncthreads();
  }

  // C/D layout: col = lane&15, row = (lane>>4)*4 + r   [verified round 1]
  const int cr = (lane >> 4) * 4;
  const int cc = lane & 15;
#pragma unroll
  for (int i = 0; i < 4; ++i)
#pragma unroll
    for (int j = 0; j < 4; ++j)
#pragma unroll
      for (int r = 0; r < 4; ++r) {
        size_t row = (size_t)(m0 + wm + i * 16 + cr + r);
        size_t col = (size_t)(n0 + wn + j * 16 + cc);
        if constexpr (OUT_F32)
          ((float*)Cp)[row * N + col] = acc[i][j][r];
        else
          ((unsigned short*)Cp)[row * N + col] = f2b(acc[i][j][r]);
      }
}

__global__ __launch_bounds__(256) void proj_gemm_b(
    const unsigned short* __restrict__ qb, const unsigned short* __restrict__ kb,
    const unsigned short* __restrict__ vb, const unsigned short* __restrict__ Wqb,
    const unsigned short* __restrict__ Wkb, const unsigned short* __restrict__ Wvb,
    unsigned short* __restrict__ qh, unsigned short* __restrict__ kh,
    unsigned short* __restrict__ vh) {
  const unsigned short *A, *W;
  unsigned short* C;
  if (blockIdx.z == 0)      { A = qb; W = Wqb; C = qh; }
  else if (blockIdx.z == 1) { A = kb; W = Wkb; C = kh; }
  else                      { A = vb; W = Wvb; C = vh; }
  gemm_lds_body<false>(A, W, C);
}

__global__ __launch_bounds__(256) void out_gemm_b(const unsigned short* __restrict__ attn,
                                                  const unsigned short* __restrict__ Wob,
                                                  float* __restrict__ out) {
  gemm_lds_body<true>(attn, Wob, out);
}

// ---------------- per-token head-axis attention (unchanged, verified) --------
__global__ __launch_bounds__(256) void attn_tok(const unsigned short* __restrict__ qh,
                                                const unsigned short* __restrict__ kh,
                                                const unsigned short* __restrict__ vh,
                                                const float* __restrict__ mask,
                                                unsigned short* __restrict__ attn) {
  __shared__ float P[4][16][17];
  __shared__ __align__(16) unsigned short Vs[4][16 * 64];
  const int lane = threadIdx.x & 63;
  const int wid  = threadIdx.x >> 6;
  const size_t tok = (size_t)blockIdx.x * 4 + wid;

  const unsigned short* qp = qh + tok * kD;
  const unsigned short* kp = kh + tok * kD;
  const unsigned short* vp = vh + tok * kD;

  {
    const s16x8* src = (const s16x8*)vp;
    s16x8 a = src[2 * lane], b = src[2 * lane + 1];
    s16x8* dst = (s16x8*)Vs[wid];
    dst[2 * lane] = a;
    dst[2 * lane + 1] = b;
  }

  const int fr = lane & 15;
  const int fk = (lane >> 4) * 8;
  s16x8 a0 = *(const s16x8*)(qp + fr * kDH + fk);
  s16x8 a1 = *(const s16x8*)(qp + fr * kDH + 32 + fk);
  s16x8 b0 = *(const s16x8*)(kp + fr * kDH + fk);
  s16x8 b1 = *(const s16x8*)(kp + fr * kDH + 32 + fk);
  f32x4 s = {0.f, 0.f, 0.f, 0.f};
  s = __builtin_amdgcn_mfma_f32_16x16x32_bf16(a0, b0, s, 0, 0, 0);
  s = __builtin_amdgcn_mfma_f32_16x16x32_bf16(a1, b1, s, 0, 0, 0);

  const int cr = (lane >> 4) * 4;
  const int cc = lane & 15;
  float p[4];
#pragma unroll
  for (int r = 0; r < 4; ++r) {
    float val = s[r] * 0.125f * mask[(cr + r) * kH + cc];
    float mx = val;
#pragma unroll
    for (int d = 1; d < 16; d <<= 1) mx = fmaxf(mx, __shfl_xor(mx, d));
    float e = __expf(val - mx);
    float sum = e;
#pragma unroll
    for (int d = 1; d < 16; d <<= 1) sum += __shfl_xor(sum, d);
    p[r] = e / sum;
  }
#pragma unroll
  for (int r = 0; r < 4; ++r) P[wid][cr + r][cc] = p[r];

  const int h  = lane >> 2;
  const int d0 = (lane & 3) * 16;
  float o[16];
#pragma unroll
  for (int i = 0; i < 16; ++i) o[i] = 0.f;
#pragma unroll
  for (int g = 0; g < 16; ++g) {
    float pg = P[wid][h][g];
    s16x8 v0 = *(const s16x8*)(Vs[wid] + g * kDH + d0);
    s16x8 v1 = *(const s16x8*)(Vs[wid] + g * kDH + d0 + 8);
#pragma unroll
    for (int dd = 0; dd < 8; ++dd) {
      o[dd]     += pg * b2f((unsigned short)v0[dd]);
      o[8 + dd] += pg * b2f((unsigned short)v1[dd]);
    }
  }
  unsigned short* op = attn + tok * kD + h * kDH + d0;
  s16x8 r0, r1;
#pragma unroll
  for (int dd = 0; dd < 8; ++dd) {
    r0[dd] = (short)f2b(o[dd]);
    r1[dd] = (short)f2b(o[dd + 8]);
  }
  *(s16x8*)op = r0;
  *(s16x8*)(op + 8) = r1;
}

// ---------------- fallback (round-1 verified path, fused-cvt GEMM) ----------
constexpr int LDSP = BK + 8;
__device__ __forceinline__ void cvt16_store(const float* __restrict__ g, short* __restrict__ l) {
  const f32x4* s4 = (const f32x4*)g;
  f32x4 f0 = s4[0], f1 = s4[1], f2 = s4[2], f3 = s4[3];
  s16x8 o0, o1;
#pragma unroll
  for (int i = 0; i < 4; ++i) {
    o0[i]     = (short)f2b(f0[i]);
    o0[4 + i] = (short)f2b(f1[i]);
    o1[i]     = (short)f2b(f2[i]);
    o1[4 + i] = (short)f2b(f3[i]);
  }
  *(s16x8*)l = o0;
  *(s16x8*)(l + 8) = o1;
}

template <bool A_BF16, bool OUT_F32>
__device__ __forceinline__ void gemm_body_cvt(const void* __restrict__ Ap,
                                              const float* __restrict__ Wp,
                                              void* __restrict__ Cp) {
  constexpr int N = kD, K = kD;
  __shared__ short As[BM * LDSP];
  __shared__ short Bs[BN * LDSP];
  const int t  = threadIdx.x;
  const int m0 = blockIdx.y * BM;
  const int n0 = blockIdx.x * BN;
  const int srow = t >> 1;
  const int scol = (t & 1) * 16;
  const int lane = t & 63;
  const int wid  = t >> 6;
  const int wm   = (wid >> 1) * 64;
  const int wn   = (wid & 1) * 64;
  const int fr   = lane & 15;
  const int fk   = (lane >> 4) * 8;

  f32x4 acc[4][4];
#pragma unroll
  for (int i = 0; i < 4; ++i)
#pragma unroll
    for (int j = 0; j < 4; ++j) acc[i][j] = (f32x4){0.f, 0.f, 0.f, 0.f};

  for (int k0 = 0; k0 < K; k0 += BK) {
    if constexpr (A_BF16) {
      const unsigned short* Ab = (const unsigned short*)Ap;
      const s16x8* src = (const s16x8*)(Ab + (size_t)(m0 + srow) * K + k0 + scol);
      s16x8 v0 = src[0], v1 = src[1];
      *(s16x8*)(As + srow * LDSP + scol) = v0;
      *(s16x8*)(As + srow * LDSP + scol + 8) = v1;
    } else {
      cvt16_store((const float*)Ap + (size_t)(m0 + srow) * K + k0 + scol,
                  As + srow * LDSP + scol);
    }
    cvt16_store(Wp + (size_t)(n0 + srow) * K + k0 + scol, Bs + srow * LDSP + scol);
    __syncthreads();
    s16x8 af[4], bw[4];
#pragma unroll
    for (int i = 0; i < 4; ++i)
      af[i] = *(const s16x8*)(As + (wm + i * 16 + fr) * LDSP + fk);
#pragma unroll
    for (int j = 0; j < 4; ++j)
      bw[j] = *(const s16x8*)(Bs + (wn + j * 16 + fr) * LDSP + fk);
#pragma unroll
    for (int i = 0; i < 4; ++i)
#pragma unroll
      for (int j = 0; j < 4; ++j)
        acc[i][j] = __builtin_amdgcn_mfma_f32_16x16x32_bf16(af[i], bw[j], acc[i][j], 0, 0, 0);
    __syncthreads();
  }
  const int cr = (lane >> 4) * 4;
  const int cc = lane & 15;
#pragma unroll
  for (int i = 0; i < 4; ++i)
#pragma unroll
    for (int j = 0; j < 4; ++j)
#pragma unroll
      for (int r = 0; r < 4; ++r) {
        size_t row = (size_t)(m0 + wm + i * 16 + cr + r);
        size_t col = (size_t)(n0 + wn + j * 16 + cc);
        if constexpr (OUT_F32)
          ((float*)Cp)[row * N + col] = acc[i][j][r];
        else
          ((unsigned short*)Cp)[row * N + col] = f2b(acc[i][j][r]);
      }
}

__global__ __launch_bounds__(256) void proj_gemm_cvt(
    const float* __restrict__ q, const float* __restrict__ k, const float* __restrict__ v,
    const float* __restrict__ Wq, const float* __restrict__ Wk, const float* __restrict__ Wv,
    unsigned short* __restrict__ qh, unsigned short* __restrict__ kh,
    unsigned short* __restrict__ vh) {
  const float* A; const float* W; unsigned short* C;
  if (blockIdx.z == 0)      { A = q; W = Wq; C = qh; }
  else if (blockIdx.z == 1) { A = k; W = Wk; C = kh; }
  else                      { A = v; W = Wv; C = vh; }
  gemm_body_cvt<false, false>(A, W, C);
}

__global__ __launch_bounds__(256) void out_gemm_cvt(const unsigned short* __restrict__ attn,
                                                    const float* __restrict__ Wo,
                                                    float* __restrict__ out) {
  gemm_body_cvt<true, true>(attn, Wo, out);
}

}  // namespace

extern "C" void kernel_launch(void* const* d_in, const int* in_sizes, int n_in,
                              void* d_out, int out_size, void* d_ws, size_t ws_size,
                              hipStream_t stream) {
  (void)in_sizes; (void)n_in; (void)out_size;
  const float* q    = (const float*)d_in[0];
  const float* k    = (const float*)d_in[1];
  const float* v    = (const float*)d_in[2];
  const float* mask = (const float*)d_in[3];
  const float* Wq   = (const float*)d_in[4];
  const float* Wk   = (const float*)d_in[5];
  const float* Wv   = (const float*)d_in[6];
  const float* Wo   = (const float*)d_in[7];

  const size_t need = (6 * PER + 4 * WSZ) * sizeof(unsigned short);  // ~210 MB
  if (ws_size >= need) {
    unsigned short* qb  = (unsigned short*)d_ws;          // ws layout (bf16 elems):
    unsigned short* kb  = qb + PER;                       // qb kb vb | Wq Wk Wv Wo | qh kh vh
    unsigned short* vb  = kb + PER;
    unsigned short* Wqb = vb + PER;
    unsigned short* Wkb = Wqb + WSZ;
    unsigned short* Wvb = Wkb + WSZ;
    unsigned short* Wob = Wvb + WSZ;
    unsigned short* qh  = Wob + WSZ;
    unsigned short* kh  = qh + PER;
    unsigned short* vh  = kh + PER;
    unsigned short* at  = qb;  // alias: qb is dead after proj_gemm_b (stream-ordered)

    cvt_bf16<<<2048, 256, 0, stream>>>(q, k, v, Wq, Wk, Wv, Wo, qb);
    proj_gemm_b<<<dim3(kD / BN, kM / BM, 3), 256, 0, stream>>>(qb, kb, vb, Wqb, Wkb, Wvb,
                                                               qh, kh, vh);
    attn_tok<<<dim3(kM / 4), 256, 0, stream>>>(qh, kh, vh, mask, at);
    out_gemm_b<<<dim3(kD / BN, kM / BM), 256, 0, stream>>>(at, Wob, (float*)d_out);
  } else {
    // round-1 verified fallback (fused-convert GEMMs)
    unsigned short* qh = (unsigned short*)d_ws;
    unsigned short* kh = qh + PER;
    unsigned short* vh = kh + PER;
    unsigned short* at = (ws_size >= 4 * PER * sizeof(unsigned short)) ? (vh + PER) : qh;
    proj_gemm_cvt<<<dim3(kD / BN, kM / BM, 3), 256, 0, stream>>>(q, k, v, Wq, Wk, Wv,
                                                                 qh, kh, vh);
    attn_tok<<<dim3(kM / 4), 256, 0, stream>>>(qh, kh, vh, mask, at);
    out_gemm_cvt<<<dim3(kD / BN, kM / BM), 256, 0, stream>>>(at, Wo, (float*)d_out);
  }
}

// Round 3
// 239.235 us; speedup vs baseline: 1.5980x; 1.1877x over previous
//
#include <hip/hip_runtime.h>
#include <hip/hip_bf16.h>
#include <stdint.h>

// MultiHeadAttention: B=4 S=4096 D=1024 H=16 DH=64; attention is per-token 16x16
// over the head axis. Round 3: 256x256 8-phase counted-vmcnt GEMM (T2 swizzle +
// T3/T4 schedule + T5 setprio + T1 XCD swizzle); cvt pass + per-token attn as before.

namespace {
constexpr int kD  = 1024;
constexpr int kH  = 16;
constexpr int kDH = 64;
constexpr int kM  = 4 * 4096;             // 16384 tokens
constexpr size_t PER = (size_t)kM * kD;   // q/k/v-sized elem count
constexpr size_t WSZ = (size_t)kD * kD;   // weight-sized elem count

typedef __attribute__((ext_vector_type(4))) float f32x4;
typedef __attribute__((ext_vector_type(8))) short s16x8;

__device__ __forceinline__ unsigned short f2b(float f) {
  uint32_t x = __builtin_bit_cast(uint32_t, f);
  x += 0x7fffu + ((x >> 16) & 1u);   // round-to-nearest-even
  return (unsigned short)(x >> 16);
}
__device__ __forceinline__ float b2f(unsigned short u) {
  return __builtin_bit_cast(float, (uint32_t)u << 16);
}

typedef __attribute__((address_space(3))) void as3_void;
typedef __attribute__((address_space(1))) void as1_void;
__device__ __forceinline__ void gload_lds16(const void* g, void* l) {
  // LDS dest is wave-uniform base + lane*16; global src is per-lane.
  __builtin_amdgcn_global_load_lds((const as1_void*)(uintptr_t)g,
                                   (as3_void*)(uint32_t)(uintptr_t)l, 16, 0, 0);
}

// ---------------- convert pass: 7 f32 tensors -> consecutive bf16 buffers ----
__global__ __launch_bounds__(256) void cvt_bf16(
    const float* __restrict__ q, const float* __restrict__ k, const float* __restrict__ v,
    const float* __restrict__ Wq, const float* __restrict__ Wk, const float* __restrict__ Wv,
    const float* __restrict__ Wo, unsigned short* __restrict__ out) {
  const size_t total8 = (3 * PER + 4 * WSZ) / 8;
  for (size_t i8 = (size_t)blockIdx.x * blockDim.x + threadIdx.x; i8 < total8;
       i8 += (size_t)gridDim.x * blockDim.x) {
    size_t i = i8 * 8;
    const float* s; size_t o;
    if (i < 3 * PER) {
      if (i < PER)            { s = q; o = i; }
      else if (i < 2 * PER)   { s = k; o = i - PER; }
      else                    { s = v; o = i - 2 * PER; }
    } else {
      size_t j = i - 3 * PER;
      if (j < WSZ)            { s = Wq; o = j; }
      else if (j < 2 * WSZ)   { s = Wk; o = j - WSZ; }
      else if (j < 3 * WSZ)   { s = Wv; o = j - 2 * WSZ; }
      else                    { s = Wo; o = j - 3 * WSZ; }
    }
    f32x4 f0 = ((const f32x4*)(s + o))[0];
    f32x4 f1 = ((const f32x4*)(s + o))[1];
    s16x8 r;
#pragma unroll
    for (int d = 0; d < 4; ++d) {
      r[d]     = (short)f2b(f0[d]);
      r[4 + d] = (short)f2b(f1[d]);
    }
    *(s16x8*)(out + i) = r;
  }
}

// ---------------- 256x256 8-phase GEMM: C[m,n] = sum_k A[m,k]*B[n,k] ---------
// 512 threads = 8 waves (2M x 4N), per-wave output 128x64, BK=64, 2 LDS bufs.
// Waits derived: all 8 gload_lds for tile t+1 issued at phase 0 of tile t;
// vmcnt(8) there waits exactly for tile t's 8 loads (issued one full tile ago)
// while t+1's stay in flight. Per-phase end barriers bound skew so prefetch
// into buf^1 is issued only after every wave finished reading tile t-1 from it.
constexpr int BM2 = 256, BN2 = 256, BK2 = 64;
constexpr int KT2 = kD / BK2;   // 16 K-tiles

template <bool OUT_F32>
__device__ __forceinline__ void gemm8_body(const unsigned short* __restrict__ A,
                                           const unsigned short* __restrict__ Bm,
                                           void* __restrict__ Cp) {
  constexpr int N = kD, K = kD;
  __shared__ __align__(16) unsigned short lds[65536];  // 128 KiB: 2 x (A 16K + B 16K elems)

  // T1: XCD-bijective swizzle of the 4x64 = 256-block grid (256 % 8 == 0).
  const int lin = blockIdx.y * gridDim.x + blockIdx.x;   // 0..255
  const int xcd = lin & 7;
  const int idx = lin >> 3;                              // 0..31
  const int m0 = (xcd * 8 + (idx >> 2)) * BM2;
  const int n0 = (idx & 3) * BN2;

  const int t    = threadIdx.x;
  const int lane = t & 63;
  const int w    = t >> 6;        // 0..7
  const int wm   = w >> 2;        // 0..1  (M half)
  const int wn   = w & 3;         // 0..3  (N quarter)

  // staging: wave w stages A rows [w*32,w*32+32) and B rows likewise, 4 chunks
  // of 8 rows x 128B each. Linear LDS write (lane*16); global source carries
  // the inverse of the read-side XOR swizzle (slot ^ row&7)  [rule #21].
  const int srow  = lane >> 3;                // 0..7 row within chunk
  const int sslot = (lane & 7) ^ srow;        // pre-swizzled 16B slot
  const unsigned short* gA = A  + (size_t)(m0 + w * 32 + srow) * K + sslot * 8;
  const unsigned short* gB = Bm + (size_t)(n0 + w * 32 + srow) * K + sslot * 8;

  f32x4 acc[8][4];
#pragma unroll
  for (int i = 0; i < 8; ++i)
#pragma unroll
    for (int j = 0; j < 4; ++j) acc[i][j] = (f32x4){0.f, 0.f, 0.f, 0.f};

  const int fr     = lane & 15;
  const int fkslot = lane >> 4;               // 0..3 (16B slot within 64B half)

  auto stage = [&](int buf, int k0) {
    const int ab = buf * 32768 + w * 2048;    // elem offsets
    const int bb = ab + 16384;
#pragma unroll
    for (int i = 0; i < 4; ++i)
      gload_lds16(gA + k0 + (size_t)i * 8 * K, lds + ab + i * 512);
#pragma unroll
    for (int i = 0; i < 4; ++i)
      gload_lds16(gB + k0 + (size_t)i * 8 * K, lds + bb + i * 512);
  };

  auto rdA = [&](int cb, int mi, int kk) -> s16x8 {
    int ra = wm * 128 + mi * 16 + fr;
    int slot = (kk * 4 + fkslot) ^ (ra & 7);
    return *(const s16x8*)(lds + cb + ra * 64 + slot * 8);
  };
  auto rdB = [&](int cb, int nj, int kk) -> s16x8 {
    int rb = wn * 64 + nj * 16 + fr;
    int slot = (kk * 4 + fkslot) ^ (rb & 7);
    return *(const s16x8*)(lds + cb + 16384 + rb * 64 + slot * 8);
  };

  stage(0, 0);   // prologue: tile 0 -> buf 0 (waited at first phase-0 vmcnt)

  for (int tt = 0; tt < KT2; ++tt) {
    const int cb = (tt & 1) * 32768;
    s16x8 bw[4][2];
    // ---------------- phase 0 ----------------
    if (tt + 1 < KT2) {
      stage((tt + 1) & 1, (tt + 1) * BK2);              // 8 loads for t+1
      asm volatile("s_waitcnt vmcnt(8)" ::: "memory");  // tile t landed; t+1 in flight
    } else {
      asm volatile("s_waitcnt vmcnt(0)" ::: "memory");  // last tile: drain
    }
    __builtin_amdgcn_s_barrier();                        // everyone's tile-t data visible
    {
#pragma unroll
      for (int nj = 0; nj < 4; ++nj)
#pragma unroll
        for (int kk = 0; kk < 2; ++kk) bw[nj][kk] = rdB(cb, nj, kk);
      s16x8 af[2][2];
#pragma unroll
      for (int m2 = 0; m2 < 2; ++m2)
#pragma unroll
        for (int kk = 0; kk < 2; ++kk) af[m2][kk] = rdA(cb, m2, kk);
      asm volatile("s_waitcnt lgkmcnt(0)" ::: "memory");
      __builtin_amdgcn_sched_barrier(0);
      __builtin_amdgcn_s_setprio(1);
#pragma unroll
      for (int m2 = 0; m2 < 2; ++m2)
#pragma unroll
        for (int nj = 0; nj < 4; ++nj)
#pragma unroll
          for (int kk = 0; kk < 2; ++kk)
            acc[m2][nj] =
                __builtin_amdgcn_mfma_f32_16x16x32_bf16(af[m2][kk], bw[nj][kk], acc[m2][nj], 0, 0, 0);
      __builtin_amdgcn_s_setprio(0);
    }
    __builtin_amdgcn_s_barrier();
    // ---------------- phases 1..3 ----------------
#pragma unroll
    for (int q = 1; q < 4; ++q) {
      s16x8 af[2][2];
#pragma unroll
      for (int m2 = 0; m2 < 2; ++m2)
#pragma unroll
        for (int kk = 0; kk < 2; ++kk) af[m2][kk] = rdA(cb, q * 2 + m2, kk);
      __builtin_amdgcn_s_barrier();
      asm volatile("s_waitcnt lgkmcnt(0)" ::: "memory");
      __builtin_amdgcn_sched_barrier(0);
      __builtin_amdgcn_s_setprio(1);
#pragma unroll
      for (int m2 = 0; m2 < 2; ++m2)
#pragma unroll
        for (int nj = 0; nj < 4; ++nj)
#pragma unroll
          for (int kk = 0; kk < 2; ++kk)
            acc[q * 2 + m2][nj] =
                __builtin_amdgcn_mfma_f32_16x16x32_bf16(af[m2][kk], bw[nj][kk],
                                                        acc[q * 2 + m2][nj], 0, 0, 0);
      __builtin_amdgcn_s_setprio(0);
      __builtin_amdgcn_s_barrier();
    }
  }

  // C/D layout: col = lane&15, row = (lane>>4)*4 + r   [verified rounds 1-2]
  const int cr = (lane >> 4) * 4;
  const int cc = lane & 15;
#pragma unroll
  for (int mi = 0; mi < 8; ++mi)
#pragma unroll
    for (int nj = 0; nj < 4; ++nj)
#pragma unroll
      for (int r = 0; r < 4; ++r) {
        size_t row = (size_t)(m0 + wm * 128 + mi * 16 + cr + r);
        size_t col = (size_t)(n0 + wn * 64 + nj * 16 + cc);
        if constexpr (OUT_F32)
          ((float*)Cp)[row * N + col] = acc[mi][nj][r];
        else
          ((unsigned short*)Cp)[row * N + col] = f2b(acc[mi][nj][r]);
      }
}

__global__ __launch_bounds__(512, 2) void proj_gemm8(
    const unsigned short* __restrict__ qb, const unsigned short* __restrict__ kb,
    const unsigned short* __restrict__ vb, const unsigned short* __restrict__ Wqb,
    const unsigned short* __restrict__ Wkb, const unsigned short* __restrict__ Wvb,
    unsigned short* __restrict__ qh, unsigned short* __restrict__ kh,
    unsigned short* __restrict__ vh) {
  const unsigned short *A, *W;
  unsigned short* C;
  if (blockIdx.z == 0)      { A = qb; W = Wqb; C = qh; }
  else if (blockIdx.z == 1) { A = kb; W = Wkb; C = kh; }
  else                      { A = vb; W = Wvb; C = vh; }
  gemm8_body<false>(A, W, C);
}

__global__ __launch_bounds__(512, 2) void out_gemm8(const unsigned short* __restrict__ attn,
                                                    const unsigned short* __restrict__ Wob,
                                                    float* __restrict__ out) {
  gemm8_body<true>(attn, Wob, out);
}

// ---------------- per-token head-axis attention (verified rounds 1-2) --------
__global__ __launch_bounds__(256) void attn_tok(const unsigned short* __restrict__ qh,
                                                const unsigned short* __restrict__ kh,
                                                const unsigned short* __restrict__ vh,
                                                const float* __restrict__ mask,
                                                unsigned short* __restrict__ attn) {
  __shared__ float P[4][16][17];
  __shared__ __align__(16) unsigned short Vs[4][16 * 64];
  const int lane = threadIdx.x & 63;
  const int wid  = threadIdx.x >> 6;
  const size_t tok = (size_t)blockIdx.x * 4 + wid;

  const unsigned short* qp = qh + tok * kD;
  const unsigned short* kp = kh + tok * kD;
  const unsigned short* vp = vh + tok * kD;

  {
    const s16x8* src = (const s16x8*)vp;
    s16x8 a = src[2 * lane], b = src[2 * lane + 1];
    s16x8* dst = (s16x8*)Vs[wid];
    dst[2 * lane] = a;
    dst[2 * lane + 1] = b;
  }

  const int fr = lane & 15;
  const int fk = (lane >> 4) * 8;
  s16x8 a0 = *(const s16x8*)(qp + fr * kDH + fk);
  s16x8 a1 = *(const s16x8*)(qp + fr * kDH + 32 + fk);
  s16x8 b0 = *(const s16x8*)(kp + fr * kDH + fk);
  s16x8 b1 = *(const s16x8*)(kp + fr * kDH + 32 + fk);
  f32x4 s = {0.f, 0.f, 0.f, 0.f};
  s = __builtin_amdgcn_mfma_f32_16x16x32_bf16(a0, b0, s, 0, 0, 0);
  s = __builtin_amdgcn_mfma_f32_16x16x32_bf16(a1, b1, s, 0, 0, 0);

  const int cr = (lane >> 4) * 4;
  const int cc = lane & 15;
  float p[4];
#pragma unroll
  for (int r = 0; r < 4; ++r) {
    float val = s[r] * 0.125f * mask[(cr + r) * kH + cc];
    float mx = val;
#pragma unroll
    for (int d = 1; d < 16; d <<= 1) mx = fmaxf(mx, __shfl_xor(mx, d));
    float e = __expf(val - mx);
    float sum = e;
#pragma unroll
    for (int d = 1; d < 16; d <<= 1) sum += __shfl_xor(sum, d);
    p[r] = e / sum;
  }
#pragma unroll
  for (int r = 0; r < 4; ++r) P[wid][cr + r][cc] = p[r];

  const int h  = lane >> 2;
  const int d0 = (lane & 3) * 16;
  float o[16];
#pragma unroll
  for (int i = 0; i < 16; ++i) o[i] = 0.f;
#pragma unroll
  for (int g = 0; g < 16; ++g) {
    float pg = P[wid][h][g];
    s16x8 v0 = *(const s16x8*)(Vs[wid] + g * kDH + d0);
    s16x8 v1 = *(const s16x8*)(Vs[wid] + g * kDH + d0 + 8);
#pragma unroll
    for (int dd = 0; dd < 8; ++dd) {
      o[dd]     += pg * b2f((unsigned short)v0[dd]);
      o[8 + dd] += pg * b2f((unsigned short)v1[dd]);
    }
  }
  unsigned short* op = attn + tok * kD + h * kDH + d0;
  s16x8 r0, r1;
#pragma unroll
  for (int dd = 0; dd < 8; ++dd) {
    r0[dd] = (short)f2b(o[dd]);
    r1[dd] = (short)f2b(o[dd + 8]);
  }
  *(s16x8*)op = r0;
  *(s16x8*)(op + 8) = r1;
}

// ---------------- fallback (round-1 verified path, fused-cvt GEMM) ----------
constexpr int BM = 128, BN = 128, BK = 32;
constexpr int LDSP = BK + 8;
__device__ __forceinline__ void cvt16_store(const float* __restrict__ g, short* __restrict__ l) {
  const f32x4* s4 = (const f32x4*)g;
  f32x4 f0 = s4[0], f1 = s4[1], f2 = s4[2], f3 = s4[3];
  s16x8 o0, o1;
#pragma unroll
  for (int i = 0; i < 4; ++i) {
    o0[i]     = (short)f2b(f0[i]);
    o0[4 + i] = (short)f2b(f1[i]);
    o1[i]     = (short)f2b(f2[i]);
    o1[4 + i] = (short)f2b(f3[i]);
  }
  *(s16x8*)l = o0;
  *(s16x8*)(l + 8) = o1;
}

template <bool A_BF16, bool OUT_F32>
__device__ __forceinline__ void gemm_body_cvt(const void* __restrict__ Ap,
                                              const float* __restrict__ Wp,
                                              void* __restrict__ Cp) {
  constexpr int N = kD, K = kD;
  __shared__ short As[BM * LDSP];
  __shared__ short Bs[BN * LDSP];
  const int t  = threadIdx.x;
  const int m0 = blockIdx.y * BM;
  const int n0 = blockIdx.x * BN;
  const int srow = t >> 1;
  const int scol = (t & 1) * 16;
  const int lane = t & 63;
  const int wid  = t >> 6;
  const int wm   = (wid >> 1) * 64;
  const int wn   = (wid & 1) * 64;
  const int fr   = lane & 15;
  const int fk   = (lane >> 4) * 8;

  f32x4 acc[4][4];
#pragma unroll
  for (int i = 0; i < 4; ++i)
#pragma unroll
    for (int j = 0; j < 4; ++j) acc[i][j] = (f32x4){0.f, 0.f, 0.f, 0.f};

  for (int k0 = 0; k0 < K; k0 += BK) {
    if constexpr (A_BF16) {
      const unsigned short* Ab = (const unsigned short*)Ap;
      const s16x8* src = (const s16x8*)(Ab + (size_t)(m0 + srow) * K + k0 + scol);
      s16x8 v0 = src[0], v1 = src[1];
      *(s16x8*)(As + srow * LDSP + scol) = v0;
      *(s16x8*)(As + srow * LDSP + scol + 8) = v1;
    } else {
      cvt16_store((const float*)Ap + (size_t)(m0 + srow) * K + k0 + scol,
                  As + srow * LDSP + scol);
    }
    cvt16_store(Wp + (size_t)(n0 + srow) * K + k0 + scol, Bs + srow * LDSP + scol);
    __syncthreads();
    s16x8 af[4], bw[4];
#pragma unroll
    for (int i = 0; i < 4; ++i)
      af[i] = *(const s16x8*)(As + (wm + i * 16 + fr) * LDSP + fk);
#pragma unroll
    for (int j = 0; j < 4; ++j)
      bw[j] = *(const s16x8*)(Bs + (wn + j * 16 + fr) * LDSP + fk);
#pragma unroll
    for (int i = 0; i < 4; ++i)
#pragma unroll
      for (int j = 0; j < 4; ++j)
        acc[i][j] = __builtin_amdgcn_mfma_f32_16x16x32_bf16(af[i], bw[j], acc[i][j], 0, 0, 0);
    __syncthreads();
  }
  const int cr = (lane >> 4) * 4;
  const int cc = lane & 15;
#pragma unroll
  for (int i = 0; i < 4; ++i)
#pragma unroll
    for (int j = 0; j < 4; ++j)
#pragma unroll
      for (int r = 0; r < 4; ++r) {
        size_t row = (size_t)(m0 + wm + i * 16 + cr + r);
        size_t col = (size_t)(n0 + wn + j * 16 + cc);
        if constexpr (OUT_F32)
          ((float*)Cp)[row * N + col] = acc[i][j][r];
        else
          ((unsigned short*)Cp)[row * N + col] = f2b(acc[i][j][r]);
      }
}

__global__ __launch_bounds__(256) void proj_gemm_cvt(
    const float* __restrict__ q, const float* __restrict__ k, const float* __restrict__ v,
    const float* __restrict__ Wq, const float* __restrict__ Wk, const float* __restrict__ Wv,
    unsigned short* __restrict__ qh, unsigned short* __restrict__ kh,
    unsigned short* __restrict__ vh) {
  const float* A; const float* W; unsigned short* C;
  if (blockIdx.z == 0)      { A = q; W = Wq; C = qh; }
  else if (blockIdx.z == 1) { A = k; W = Wk; C = kh; }
  else                      { A = v; W = Wv; C = vh; }
  gemm_body_cvt<false, false>(A, W, C);
}

__global__ __launch_bounds__(256) void out_gemm_cvt(const unsigned short* __restrict__ attn,
                                                    const float* __restrict__ Wo,
                                                    float* __restrict__ out) {
  gemm_body_cvt<true, true>(attn, Wo, out);
}

}  // namespace

extern "C" void kernel_launch(void* const* d_in, const int* in_sizes, int n_in,
                              void* d_out, int out_size, void* d_ws, size_t ws_size,
                              hipStream_t stream) {
  (void)in_sizes; (void)n_in; (void)out_size;
  const float* q    = (const float*)d_in[0];
  const float* k    = (const float*)d_in[1];
  const float* v    = (const float*)d_in[2];
  const float* mask = (const float*)d_in[3];
  const float* Wq   = (const float*)d_in[4];
  const float* Wk   = (const float*)d_in[5];
  const float* Wv   = (const float*)d_in[6];
  const float* Wo   = (const float*)d_in[7];

  const size_t need = (6 * PER + 4 * WSZ) * sizeof(unsigned short);  // ~210 MB
  if (ws_size >= need) {
    unsigned short* qb  = (unsigned short*)d_ws;          // ws layout (bf16 elems):
    unsigned short* kb  = qb + PER;                       // qb kb vb | Wq Wk Wv Wo | qh kh vh
    unsigned short* vb  = kb + PER;
    unsigned short* Wqb = vb + PER;
    unsigned short* Wkb = Wqb + WSZ;
    unsigned short* Wvb = Wkb + WSZ;
    unsigned short* Wob = Wvb + WSZ;
    unsigned short* qh  = Wob + WSZ;
    unsigned short* kh  = qh + PER;
    unsigned short* vh  = kh + PER;
    unsigned short* at  = qb;  // alias: qb is dead after proj_gemm8 (stream-ordered)

    cvt_bf16<<<2048, 256, 0, stream>>>(q, k, v, Wq, Wk, Wv, Wo, qb);
    proj_gemm8<<<dim3(kD / BN2, kM / BM2, 3), 512, 0, stream>>>(qb, kb, vb, Wqb, Wkb, Wvb,
                                                                qh, kh, vh);
    attn_tok<<<dim3(kM / 4), 256, 0, stream>>>(qh, kh, vh, mask, at);
    out_gemm8<<<dim3(kD / BN2, kM / BM2), 512, 0, stream>>>(at, Wob, (float*)d_out);
  } else {
    // round-1 verified fallback (fused-convert GEMMs)
    unsigned short* qh = (unsigned short*)d_ws;
    unsigned short* kh = qh + PER;
    unsigned short* vh = kh + PER;
    unsigned short* at = (ws_size >= 4 * PER * sizeof(unsigned short)) ? (vh + PER) : qh;
    proj_gemm_cvt<<<dim3(kD / BN, kM / BM, 3), 256, 0, stream>>>(q, k, v, Wq, Wk, Wv,
                                                                 qh, kh, vh);
    attn_tok<<<dim3(kM / 4), 256, 0, stream>>>(qh, kh, vh, mask, at);
    out_gemm_cvt<<<dim3(kD / BN, kM / BM), 256, 0, stream>>>(at, Wo, (float*)d_out);
  }
}

// Round 4
// 234.807 us; speedup vs baseline: 1.6282x; 1.0189x over previous
//
#include <hip/hip_runtime.h>
#include <hip/hip_bf16.h>
#include <stdint.h>

// MultiHeadAttention: B=4 S=4096 D=1024 H=16 DH=64; attention is per-token 16x16
// over the head axis. Round 4: 2-barrier-per-K-tile GEMM schedule with
// software-pipelined A-fragment reads (afA/afB rotation) + counted vmcnt.

namespace {
constexpr int kD  = 1024;
constexpr int kH  = 16;
constexpr int kDH = 64;
constexpr int kM  = 4 * 4096;             // 16384 tokens
constexpr size_t PER = (size_t)kM * kD;   // q/k/v-sized elem count
constexpr size_t WSZ = (size_t)kD * kD;   // weight-sized elem count

typedef __attribute__((ext_vector_type(4))) float f32x4;
typedef __attribute__((ext_vector_type(8))) short s16x8;

__device__ __forceinline__ unsigned short f2b(float f) {
  uint32_t x = __builtin_bit_cast(uint32_t, f);
  x += 0x7fffu + ((x >> 16) & 1u);   // round-to-nearest-even
  return (unsigned short)(x >> 16);
}
__device__ __forceinline__ float b2f(unsigned short u) {
  return __builtin_bit_cast(float, (uint32_t)u << 16);
}

typedef __attribute__((address_space(3))) void as3_void;
typedef __attribute__((address_space(1))) void as1_void;
__device__ __forceinline__ void gload_lds16(const void* g, void* l) {
  // LDS dest is wave-uniform base + lane*16; global src is per-lane.
  __builtin_amdgcn_global_load_lds((const as1_void*)(uintptr_t)g,
                                   (as3_void*)(uint32_t)(uintptr_t)l, 16, 0, 0);
}

// ---------------- convert pass: 7 f32 tensors -> consecutive bf16 buffers ----
__global__ __launch_bounds__(256) void cvt_bf16(
    const float* __restrict__ q, const float* __restrict__ k, const float* __restrict__ v,
    const float* __restrict__ Wq, const float* __restrict__ Wk, const float* __restrict__ Wv,
    const float* __restrict__ Wo, unsigned short* __restrict__ out) {
  const size_t total8 = (3 * PER + 4 * WSZ) / 8;
  for (size_t i8 = (size_t)blockIdx.x * blockDim.x + threadIdx.x; i8 < total8;
       i8 += (size_t)gridDim.x * blockDim.x) {
    size_t i = i8 * 8;
    const float* s; size_t o;
    if (i < 3 * PER) {
      if (i < PER)            { s = q; o = i; }
      else if (i < 2 * PER)   { s = k; o = i - PER; }
      else                    { s = v; o = i - 2 * PER; }
    } else {
      size_t j = i - 3 * PER;
      if (j < WSZ)            { s = Wq; o = j; }
      else if (j < 2 * WSZ)   { s = Wk; o = j - WSZ; }
      else if (j < 3 * WSZ)   { s = Wv; o = j - 2 * WSZ; }
      else                    { s = Wo; o = j - 3 * WSZ; }
    }
    f32x4 f0 = ((const f32x4*)(s + o))[0];
    f32x4 f1 = ((const f32x4*)(s + o))[1];
    s16x8 r;
#pragma unroll
    for (int d = 0; d < 4; ++d) {
      r[d]     = (short)f2b(f0[d]);
      r[4 + d] = (short)f2b(f1[d]);
    }
    *(s16x8*)(out + i) = r;
  }
}

// ---------------- 256x256 GEMM, 2 barriers/K-tile: C[m,n] = sum_k A[m,k]*B[n,k]
// 512 threads = 8 waves (2M x 4N), per-wave output 128x64, BK=64, 2 LDS bufs.
// Tile t: barrier(a) [all waves done reading buf^1 = tile t-1] -> stage(t+1)
// into buf^1 -> vmcnt(8) [tile t's 8 loads retired, in-order] -> barrier(b)
// [tile t visible] -> 24 ds_reads software-pipelined among 4 MFMA clusters
// (compiler inserts counted lgkmcnt). No per-phase barriers: within a tile all
// LDS reads target immutable data.
constexpr int BM2 = 256, BN2 = 256, BK2 = 64;
constexpr int KT2 = kD / BK2;   // 16 K-tiles

template <bool OUT_F32>
__device__ __forceinline__ void gemm8_body(const unsigned short* __restrict__ A,
                                           const unsigned short* __restrict__ Bm,
                                           void* __restrict__ Cp) {
  constexpr int N = kD, K = kD;
  __shared__ __align__(16) unsigned short lds[65536];  // 128 KiB: 2 x (A 16K + B 16K elems)

  // T1: XCD-bijective swizzle of the 4x64 = 256-block grid (256 % 8 == 0).
  const int lin = blockIdx.y * gridDim.x + blockIdx.x;   // 0..255
  const int xcd = lin & 7;
  const int idx = lin >> 3;                              // 0..31
  const int m0 = (xcd * 8 + (idx >> 2)) * BM2;
  const int n0 = (idx & 3) * BN2;

  const int t    = threadIdx.x;
  const int lane = t & 63;
  const int w    = t >> 6;        // 0..7
  const int wm   = w >> 2;        // 0..1  (M half)
  const int wn   = w & 3;         // 0..3  (N quarter)

  // staging: wave w stages A rows [w*32,w*32+32) and B rows likewise, 4 chunks
  // of 8 rows x 128B each. Linear LDS write (lane*16); global source carries
  // the inverse of the read-side XOR swizzle (slot ^ row&7)  [rule #21].
  const int srow  = lane >> 3;                // 0..7 row within chunk
  const int sslot = (lane & 7) ^ srow;        // pre-swizzled 16B slot
  const unsigned short* gA = A  + (size_t)(m0 + w * 32 + srow) * K + sslot * 8;
  const unsigned short* gB = Bm + (size_t)(n0 + w * 32 + srow) * K + sslot * 8;

  f32x4 acc[8][4];
#pragma unroll
  for (int i = 0; i < 8; ++i)
#pragma unroll
    for (int j = 0; j < 4; ++j) acc[i][j] = (f32x4){0.f, 0.f, 0.f, 0.f};

  const int fr     = lane & 15;
  const int fkslot = lane >> 4;               // 0..3 (16B slot within 64B half)

  auto stage = [&](int buf, int k0) {
    const int ab = buf * 32768 + w * 2048;    // elem offsets
    const int bb = ab + 16384;
#pragma unroll
    for (int i = 0; i < 4; ++i)
      gload_lds16(gA + k0 + (size_t)i * 8 * K, lds + ab + i * 512);
#pragma unroll
    for (int i = 0; i < 4; ++i)
      gload_lds16(gB + k0 + (size_t)i * 8 * K, lds + bb + i * 512);
  };

  auto rdA = [&](int cb, int mi, int kk) -> s16x8 {
    int ra = wm * 128 + mi * 16 + fr;
    int slot = (kk * 4 + fkslot) ^ (ra & 7);
    return *(const s16x8*)(lds + cb + ra * 64 + slot * 8);
  };
  auto rdB = [&](int cb, int nj, int kk) -> s16x8 {
    int rb = wn * 64 + nj * 16 + fr;
    int slot = (kk * 4 + fkslot) ^ (rb & 7);
    return *(const s16x8*)(lds + cb + 16384 + rb * 64 + slot * 8);
  };

  stage(0, 0);   // prologue: tile 0 -> buf 0

  for (int tt = 0; tt < KT2; ++tt) {
    const int cb = (tt & 1) * 32768;

    __builtin_amdgcn_s_barrier();     // (a) every wave done reading buf^1 (t-1)
    if (tt + 1 < KT2) {
      stage((tt + 1) & 1, (tt + 1) * BK2);              // 8 loads for t+1 -> buf^1
      asm volatile("s_waitcnt vmcnt(8)" ::: "memory");  // tile t's loads retired
    } else {
      asm volatile("s_waitcnt vmcnt(0)" ::: "memory");  // last tile: drain
    }
    __builtin_amdgcn_s_barrier();     // (b) tile t visible to all waves

    // B fragments (held across all 4 clusters) + first two A subtiles.
    s16x8 bw[4][2], afA[2][2], afB[2][2];
#pragma unroll
    for (int nj = 0; nj < 4; ++nj)
#pragma unroll
      for (int kk = 0; kk < 2; ++kk) bw[nj][kk] = rdB(cb, nj, kk);
#pragma unroll
    for (int m2 = 0; m2 < 2; ++m2)
#pragma unroll
      for (int kk = 0; kk < 2; ++kk) afA[m2][kk] = rdA(cb, m2, kk);
#pragma unroll
    for (int m2 = 0; m2 < 2; ++m2)
#pragma unroll
      for (int kk = 0; kk < 2; ++kk) afB[m2][kk] = rdA(cb, 2 + m2, kk);

    // cluster 0: mi 0..1 (afA); prefetch of afA for cluster 2 follows it.
    __builtin_amdgcn_s_setprio(1);
#pragma unroll
    for (int m2 = 0; m2 < 2; ++m2)
#pragma unroll
      for (int nj = 0; nj < 4; ++nj)
#pragma unroll
        for (int kk = 0; kk < 2; ++kk)
          acc[m2][nj] =
              __builtin_amdgcn_mfma_f32_16x16x32_bf16(afA[m2][kk], bw[nj][kk], acc[m2][nj], 0, 0, 0);
    __builtin_amdgcn_s_setprio(0);
#pragma unroll
    for (int m2 = 0; m2 < 2; ++m2)
#pragma unroll
      for (int kk = 0; kk < 2; ++kk) afA[m2][kk] = rdA(cb, 4 + m2, kk);

    // cluster 1: mi 2..3 (afB)
    __builtin_amdgcn_s_setprio(1);
#pragma unroll
    for (int m2 = 0; m2 < 2; ++m2)
#pragma unroll
      for (int nj = 0; nj < 4; ++nj)
#pragma unroll
        for (int kk = 0; kk < 2; ++kk)
          acc[2 + m2][nj] =
              __builtin_amdgcn_mfma_f32_16x16x32_bf16(afB[m2][kk], bw[nj][kk], acc[2 + m2][nj], 0, 0, 0);
    __builtin_amdgcn_s_setprio(0);
#pragma unroll
    for (int m2 = 0; m2 < 2; ++m2)
#pragma unroll
      for (int kk = 0; kk < 2; ++kk) afB[m2][kk] = rdA(cb, 6 + m2, kk);

    // cluster 2: mi 4..5 (afA)
    __builtin_amdgcn_s_setprio(1);
#pragma unroll
    for (int m2 = 0; m2 < 2; ++m2)
#pragma unroll
      for (int nj = 0; nj < 4; ++nj)
#pragma unroll
        for (int kk = 0; kk < 2; ++kk)
          acc[4 + m2][nj] =
              __builtin_amdgcn_mfma_f32_16x16x32_bf16(afA[m2][kk], bw[nj][kk], acc[4 + m2][nj], 0, 0, 0);
    __builtin_amdgcn_s_setprio(0);

    // cluster 3: mi 6..7 (afB)
    __builtin_amdgcn_s_setprio(1);
#pragma unroll
    for (int m2 = 0; m2 < 2; ++m2)
#pragma unroll
      for (int nj = 0; nj < 4; ++nj)
#pragma unroll
        for (int kk = 0; kk < 2; ++kk)
          acc[6 + m2][nj] =
              __builtin_amdgcn_mfma_f32_16x16x32_bf16(afB[m2][kk], bw[nj][kk], acc[6 + m2][nj], 0, 0, 0);
    __builtin_amdgcn_s_setprio(0);
  }

  // C/D layout: col = lane&15, row = (lane>>4)*4 + r   [verified rounds 1-3]
  const int cr = (lane >> 4) * 4;
  const int cc = lane & 15;
#pragma unroll
  for (int mi = 0; mi < 8; ++mi)
#pragma unroll
    for (int nj = 0; nj < 4; ++nj)
#pragma unroll
      for (int r = 0; r < 4; ++r) {
        size_t row = (size_t)(m0 + wm * 128 + mi * 16 + cr + r);
        size_t col = (size_t)(n0 + wn * 64 + nj * 16 + cc);
        if constexpr (OUT_F32)
          ((float*)Cp)[row * N + col] = acc[mi][nj][r];
        else
          ((unsigned short*)Cp)[row * N + col] = f2b(acc[mi][nj][r]);
      }
}

__global__ __launch_bounds__(512, 2) void proj_gemm8(
    const unsigned short* __restrict__ qb, const unsigned short* __restrict__ kb,
    const unsigned short* __restrict__ vb, const unsigned short* __restrict__ Wqb,
    const unsigned short* __restrict__ Wkb, const unsigned short* __restrict__ Wvb,
    unsigned short* __restrict__ qh, unsigned short* __restrict__ kh,
    unsigned short* __restrict__ vh) {
  const unsigned short *A, *W;
  unsigned short* C;
  if (blockIdx.z == 0)      { A = qb; W = Wqb; C = qh; }
  else if (blockIdx.z == 1) { A = kb; W = Wkb; C = kh; }
  else                      { A = vb; W = Wvb; C = vh; }
  gemm8_body<false>(A, W, C);
}

__global__ __launch_bounds__(512, 2) void out_gemm8(const unsigned short* __restrict__ attn,
                                                    const unsigned short* __restrict__ Wob,
                                                    float* __restrict__ out) {
  gemm8_body<true>(attn, Wob, out);
}

// ---------------- per-token head-axis attention (verified rounds 1-3) --------
__global__ __launch_bounds__(256) void attn_tok(const unsigned short* __restrict__ qh,
                                                const unsigned short* __restrict__ kh,
                                                const unsigned short* __restrict__ vh,
                                                const float* __restrict__ mask,
                                                unsigned short* __restrict__ attn) {
  __shared__ float P[4][16][17];
  __shared__ __align__(16) unsigned short Vs[4][16 * 64];
  const int lane = threadIdx.x & 63;
  const int wid  = threadIdx.x >> 6;
  const size_t tok = (size_t)blockIdx.x * 4 + wid;

  const unsigned short* qp = qh + tok * kD;
  const unsigned short* kp = kh + tok * kD;
  const unsigned short* vp = vh + tok * kD;

  {
    const s16x8* src = (const s16x8*)vp;
    s16x8 a = src[2 * lane], b = src[2 * lane + 1];
    s16x8* dst = (s16x8*)Vs[wid];
    dst[2 * lane] = a;
    dst[2 * lane + 1] = b;
  }

  const int fr = lane & 15;
  const int fk = (lane >> 4) * 8;
  s16x8 a0 = *(const s16x8*)(qp + fr * kDH + fk);
  s16x8 a1 = *(const s16x8*)(qp + fr * kDH + 32 + fk);
  s16x8 b0 = *(const s16x8*)(kp + fr * kDH + fk);
  s16x8 b1 = *(const s16x8*)(kp + fr * kDH + 32 + fk);
  f32x4 s = {0.f, 0.f, 0.f, 0.f};
  s = __builtin_amdgcn_mfma_f32_16x16x32_bf16(a0, b0, s, 0, 0, 0);
  s = __builtin_amdgcn_mfma_f32_16x16x32_bf16(a1, b1, s, 0, 0, 0);

  const int cr = (lane >> 4) * 4;
  const int cc = lane & 15;
  float p[4];
#pragma unroll
  for (int r = 0; r < 4; ++r) {
    float val = s[r] * 0.125f * mask[(cr + r) * kH + cc];
    float mx = val;
#pragma unroll
    for (int d = 1; d < 16; d <<= 1) mx = fmaxf(mx, __shfl_xor(mx, d));
    float e = __expf(val - mx);
    float sum = e;
#pragma unroll
    for (int d = 1; d < 16; d <<= 1) sum += __shfl_xor(sum, d);
    p[r] = e / sum;
  }
#pragma unroll
  for (int r = 0; r < 4; ++r) P[wid][cr + r][cc] = p[r];

  const int h  = lane >> 2;
  const int d0 = (lane & 3) * 16;
  float o[16];
#pragma unroll
  for (int i = 0; i < 16; ++i) o[i] = 0.f;
#pragma unroll
  for (int g = 0; g < 16; ++g) {
    float pg = P[wid][h][g];
    s16x8 v0 = *(const s16x8*)(Vs[wid] + g * kDH + d0);
    s16x8 v1 = *(const s16x8*)(Vs[wid] + g * kDH + d0 + 8);
#pragma unroll
    for (int dd = 0; dd < 8; ++dd) {
      o[dd]     += pg * b2f((unsigned short)v0[dd]);
      o[8 + dd] += pg * b2f((unsigned short)v1[dd]);
    }
  }
  unsigned short* op = attn + tok * kD + h * kDH + d0;
  s16x8 r0, r1;
#pragma unroll
  for (int dd = 0; dd < 8; ++dd) {
    r0[dd] = (short)f2b(o[dd]);
    r1[dd] = (short)f2b(o[dd + 8]);
  }
  *(s16x8*)op = r0;
  *(s16x8*)(op + 8) = r1;
}

// ---------------- fallback (round-1 verified path, fused-cvt GEMM) ----------
constexpr int BM = 128, BN = 128, BK = 32;
constexpr int LDSP = BK + 8;
__device__ __forceinline__ void cvt16_store(const float* __restrict__ g, short* __restrict__ l) {
  const f32x4* s4 = (const f32x4*)g;
  f32x4 f0 = s4[0], f1 = s4[1], f2 = s4[2], f3 = s4[3];
  s16x8 o0, o1;
#pragma unroll
  for (int i = 0; i < 4; ++i) {
    o0[i]     = (short)f2b(f0[i]);
    o0[4 + i] = (short)f2b(f1[i]);
    o1[i]     = (short)f2b(f2[i]);
    o1[4 + i] = (short)f2b(f3[i]);
  }
  *(s16x8*)l = o0;
  *(s16x8*)(l + 8) = o1;
}

template <bool A_BF16, bool OUT_F32>
__device__ __forceinline__ void gemm_body_cvt(const void* __restrict__ Ap,
                                              const float* __restrict__ Wp,
                                              void* __restrict__ Cp) {
  constexpr int N = kD, K = kD;
  __shared__ short As[BM * LDSP];
  __shared__ short Bs[BN * LDSP];
  const int t  = threadIdx.x;
  const int m0 = blockIdx.y * BM;
  const int n0 = blockIdx.x * BN;
  const int srow = t >> 1;
  const int scol = (t & 1) * 16;
  const int lane = t & 63;
  const int wid  = t >> 6;
  const int wm   = (wid >> 1) * 64;
  const int wn   = (wid & 1) * 64;
  const int fr   = lane & 15;
  const int fk   = (lane >> 4) * 8;

  f32x4 acc[4][4];
#pragma unroll
  for (int i = 0; i < 4; ++i)
#pragma unroll
    for (int j = 0; j < 4; ++j) acc[i][j] = (f32x4){0.f, 0.f, 0.f, 0.f};

  for (int k0 = 0; k0 < K; k0 += BK) {
    if constexpr (A_BF16) {
      const unsigned short* Ab = (const unsigned short*)Ap;
      const s16x8* src = (const s16x8*)(Ab + (size_t)(m0 + srow) * K + k0 + scol);
      s16x8 v0 = src[0], v1 = src[1];
      *(s16x8*)(As + srow * LDSP + scol) = v0;
      *(s16x8*)(As + srow * LDSP + scol + 8) = v1;
    } else {
      cvt16_store((const float*)Ap + (size_t)(m0 + srow) * K + k0 + scol,
                  As + srow * LDSP + scol);
    }
    cvt16_store(Wp + (size_t)(n0 + srow) * K + k0 + scol, Bs + srow * LDSP + scol);
    __syncthreads();
    s16x8 af[4], bw[4];
#pragma unroll
    for (int i = 0; i < 4; ++i)
      af[i] = *(const s16x8*)(As + (wm + i * 16 + fr) * LDSP + fk);
#pragma unroll
    for (int j = 0; j < 4; ++j)
      bw[j] = *(const s16x8*)(Bs + (wn + j * 16 + fr) * LDSP + fk);
#pragma unroll
    for (int i = 0; i < 4; ++i)
#pragma unroll
      for (int j = 0; j < 4; ++j)
        acc[i][j] = __builtin_amdgcn_mfma_f32_16x16x32_bf16(af[i], bw[j], acc[i][j], 0, 0, 0);
    __syncthreads();
  }
  const int cr = (lane >> 4) * 4;
  const int cc = lane & 15;
#pragma unroll
  for (int i = 0; i < 4; ++i)
#pragma unroll
    for (int j = 0; j < 4; ++j)
#pragma unroll
      for (int r = 0; r < 4; ++r) {
        size_t row = (size_t)(m0 + wm + i * 16 + cr + r);
        size_t col = (size_t)(n0 + wn + j * 16 + cc);
        if constexpr (OUT_F32)
          ((float*)Cp)[row * N + col] = acc[i][j][r];
        else
          ((unsigned short*)Cp)[row * N + col] = f2b(acc[i][j][r]);
      }
}

__global__ __launch_bounds__(256) void proj_gemm_cvt(
    const float* __restrict__ q, const float* __restrict__ k, const float* __restrict__ v,
    const float* __restrict__ Wq, const float* __restrict__ Wk, const float* __restrict__ Wv,
    unsigned short* __restrict__ qh, unsigned short* __restrict__ kh,
    unsigned short* __restrict__ vh) {
  const float* A; const float* W; unsigned short* C;
  if (blockIdx.z == 0)      { A = q; W = Wq; C = qh; }
  else if (blockIdx.z == 1) { A = k; W = Wk; C = kh; }
  else                      { A = v; W = Wv; C = vh; }
  gemm_body_cvt<false, false>(A, W, C);
}

__global__ __launch_bounds__(256) void out_gemm_cvt(const unsigned short* __restrict__ attn,
                                                    const float* __restrict__ Wo,
                                                    float* __restrict__ out) {
  gemm_body_cvt<true, true>(attn, Wo, out);
}

}  // namespace

extern "C" void kernel_launch(void* const* d_in, const int* in_sizes, int n_in,
                              void* d_out, int out_size, void* d_ws, size_t ws_size,
                              hipStream_t stream) {
  (void)in_sizes; (void)n_in; (void)out_size;
  const float* q    = (const float*)d_in[0];
  const float* k    = (const float*)d_in[1];
  const float* v    = (const float*)d_in[2];
  const float* mask = (const float*)d_in[3];
  const float* Wq   = (const float*)d_in[4];
  const float* Wk   = (const float*)d_in[5];
  const float* Wv   = (const float*)d_in[6];
  const float* Wo   = (const float*)d_in[7];

  const size_t need = (6 * PER + 4 * WSZ) * sizeof(unsigned short);  // ~210 MB
  if (ws_size >= need) {
    unsigned short* qb  = (unsigned short*)d_ws;          // ws layout (bf16 elems):
    unsigned short* kb  = qb + PER;                       // qb kb vb | Wq Wk Wv Wo | qh kh vh
    unsigned short* vb  = kb + PER;
    unsigned short* Wqb = vb + PER;
    unsigned short* Wkb = Wqb + WSZ;
    unsigned short* Wvb = Wkb + WSZ;
    unsigned short* Wob = Wvb + WSZ;
    unsigned short* qh  = Wob + WSZ;
    unsigned short* kh  = qh + PER;
    unsigned short* vh  = kh + PER;
    unsigned short* at  = qb;  // alias: qb is dead after proj_gemm8 (stream-ordered)

    cvt_bf16<<<2048, 256, 0, stream>>>(q, k, v, Wq, Wk, Wv, Wo, qb);
    proj_gemm8<<<dim3(kD / BN2, kM / BM2, 3), 512, 0, stream>>>(qb, kb, vb, Wqb, Wkb, Wvb,
                                                                qh, kh, vh);
    attn_tok<<<dim3(kM / 4), 256, 0, stream>>>(qh, kh, vh, mask, at);
    out_gemm8<<<dim3(kD / BN2, kM / BM2), 512, 0, stream>>>(at, Wob, (float*)d_out);
  } else {
    // round-1 verified fallback (fused-convert GEMMs)
    unsigned short* qh = (unsigned short*)d_ws;
    unsigned short* kh = qh + PER;
    unsigned short* vh = kh + PER;
    unsigned short* at = (ws_size >= 4 * PER * sizeof(unsigned short)) ? (vh + PER) : qh;
    proj_gemm_cvt<<<dim3(kD / BN, kM / BM, 3), 256, 0, stream>>>(q, k, v, Wq, Wk, Wv,
                                                                 qh, kh, vh);
    attn_tok<<<dim3(kM / 4), 256, 0, stream>>>(qh, kh, vh, mask, at);
    out_gemm_cvt<<<dim3(kD / BN, kM / BM), 256, 0, stream>>>(at, Wo, (float*)d_out);
  }
}

// Round 5
// 210.346 us; speedup vs baseline: 1.8175x; 1.1163x over previous
//
#include <hip/hip_runtime.h>
#include <hip/hip_bf16.h>
#include <stdint.h>

// MultiHeadAttention: B=4 S=4096 D=1024 H=16 DH=64; attention is per-token 16x16
// over the head axis. Round 5: f32->bf16 conversion fused into proj A-staging
// (reg-staged, 1-tile-ahead loads, write-side swizzle); weights pre-converted by
// tiny cvt_w; 256x256 2-barrier counted-vmcnt GEMM otherwise as round 4.

namespace {
constexpr int kD  = 1024;
constexpr int kH  = 16;
constexpr int kDH = 64;
constexpr int kM  = 4 * 4096;             // 16384 tokens
constexpr size_t PER = (size_t)kM * kD;   // q/k/v-sized elem count
constexpr size_t WSZ = (size_t)kD * kD;   // weight-sized elem count

typedef __attribute__((ext_vector_type(4))) float f32x4;
typedef __attribute__((ext_vector_type(8))) short s16x8;

__device__ __forceinline__ unsigned short f2b(float f) {
  uint32_t x = __builtin_bit_cast(uint32_t, f);
  x += 0x7fffu + ((x >> 16) & 1u);   // round-to-nearest-even
  return (unsigned short)(x >> 16);
}
__device__ __forceinline__ float b2f(unsigned short u) {
  return __builtin_bit_cast(float, (uint32_t)u << 16);
}

typedef __attribute__((address_space(3))) void as3_void;
typedef __attribute__((address_space(1))) void as1_void;
__device__ __forceinline__ void gload_lds16(const void* g, void* l) {
  // LDS dest is wave-uniform base + lane*16; global src is per-lane.
  __builtin_amdgcn_global_load_lds((const as1_void*)(uintptr_t)g,
                                   (as3_void*)(uint32_t)(uintptr_t)l, 16, 0, 0);
}

// ---------------- weight convert pass: 4 f32 weight matrices -> bf16 ---------
__global__ __launch_bounds__(256) void cvt_w(
    const float* __restrict__ Wq, const float* __restrict__ Wk,
    const float* __restrict__ Wv, const float* __restrict__ Wo,
    unsigned short* __restrict__ out) {
  const size_t total8 = 4 * WSZ / 8;
  for (size_t i8 = (size_t)blockIdx.x * blockDim.x + threadIdx.x; i8 < total8;
       i8 += (size_t)gridDim.x * blockDim.x) {
    size_t i = i8 * 8;
    const float* s; size_t o;
    if (i < WSZ)            { s = Wq; o = i; }
    else if (i < 2 * WSZ)   { s = Wk; o = i - WSZ; }
    else if (i < 3 * WSZ)   { s = Wv; o = i - 2 * WSZ; }
    else                    { s = Wo; o = i - 3 * WSZ; }
    f32x4 f0 = ((const f32x4*)(s + o))[0];
    f32x4 f1 = ((const f32x4*)(s + o))[1];
    s16x8 r;
#pragma unroll
    for (int d = 0; d < 4; ++d) {
      r[d]     = (short)f2b(f0[d]);
      r[4 + d] = (short)f2b(f1[d]);
    }
    *(s16x8*)(out + i) = r;
  }
}

// ---------------- 256x256 GEMM, 2 barriers/K-tile: C[m,n] = sum_k A[m,k]*B[n,k]
// 512 threads = 8 waves (2M x 4N), per-wave output 128x64, BK=64, 2 LDS bufs.
// A_F32: A staged via reg (8x dwordx4 issued 1 tile ahead) -> cvt -> swizzled
// ds_write. Else: A via gload_lds with pre-swizzled global source (rule #21).
constexpr int BM2 = 256, BN2 = 256, BK2 = 64;
constexpr int KT2 = kD / BK2;   // 16 K-tiles

template <bool A_F32, bool OUT_F32>
__device__ __forceinline__ void gemm8_body(const void* __restrict__ Ap,
                                           const unsigned short* __restrict__ Bm,
                                           void* __restrict__ Cp) {
  constexpr int N = kD, K = kD;
  __shared__ __align__(16) unsigned short lds[65536];  // 128 KiB: 2 x (A 16K + B 16K elems)

  // T1: XCD-bijective swizzle of the 4x64 = 256-block grid (256 % 8 == 0).
  const int lin = blockIdx.y * gridDim.x + blockIdx.x;   // 0..255
  const int xcd = lin & 7;
  const int idx = lin >> 3;                              // 0..31
  const int m0 = (xcd * 8 + (idx >> 2)) * BM2;
  const int n0 = (idx & 3) * BN2;

  const int t    = threadIdx.x;
  const int lane = t & 63;
  const int w    = t >> 6;        // 0..7
  const int wm   = w >> 2;        // 0..1  (M half)
  const int wn   = w & 3;         // 0..3  (N quarter)

  // B staging (gload_lds): wave w owns rows [w*32, +32), 4 chunks of 8 rows.
  // Linear LDS write (lane*16); global source pre-swizzled (slot ^ row&7).
  const int srow  = lane >> 3;                // 0..7 row within chunk
  const int sslot = (lane & 7) ^ srow;        // pre-swizzled 16B slot
  const unsigned short* gB = Bm + (size_t)(n0 + w * 32 + srow) * K + sslot * 8;
  const unsigned short* gA_b16 =
      A_F32 ? nullptr
            : ((const unsigned short*)Ap + (size_t)(m0 + w * 32 + srow) * K + sslot * 8);
  const float* Af = A_F32 ? (const float*)Ap : nullptr;

  f32x4 acc[8][4];
#pragma unroll
  for (int i = 0; i < 8; ++i)
#pragma unroll
    for (int j = 0; j < 4; ++j) acc[i][j] = (f32x4){0.f, 0.f, 0.f, 0.f};

  const int fr     = lane & 15;
  const int fkslot = lane >> 4;               // 0..3 (16B slot within 64B half)

  f32x4 areg[8];                              // 1-tile-ahead A f32 (A_F32 only)

  auto issueA = [&](int k0) {                 // 8 global_load_dwordx4 -> areg
#pragma unroll
    for (int i = 0; i < 4; ++i) {
      const float* src =
          Af + (size_t)(m0 + w * 32 + i * 8 + (lane >> 3)) * K + k0 + (lane & 7) * 8;
      areg[2 * i]     = ((const f32x4*)src)[0];
      areg[2 * i + 1] = ((const f32x4*)src)[1];
    }
  };
  auto cvtWriteA = [&](int buf) {             // cvt 32 elems -> 4 swizzled ds_write_b128
    const int base = buf * 32768;
#pragma unroll
    for (int i = 0; i < 4; ++i) {
      const int row  = w * 32 + i * 8 + (lane >> 3);
      const int slot = (lane & 7) ^ (row & 7);
      s16x8 c;
#pragma unroll
      for (int d = 0; d < 4; ++d) {
        c[d]     = (short)f2b(areg[2 * i][d]);
        c[4 + d] = (short)f2b(areg[2 * i + 1][d]);
      }
      *(s16x8*)(lds + base + row * 64 + slot * 8) = c;
    }
  };
  auto stageA_lds = [&](int buf, int k0) {    // A bf16 via gload_lds
    const int ab = buf * 32768 + w * 2048;
#pragma unroll
    for (int i = 0; i < 4; ++i)
      gload_lds16(gA_b16 + k0 + (size_t)i * 8 * K, lds + ab + i * 512);
  };
  auto stageB = [&](int buf, int k0) {
    const int bb = buf * 32768 + 16384 + w * 2048;
#pragma unroll
    for (int i = 0; i < 4; ++i)
      gload_lds16(gB + k0 + (size_t)i * 8 * K, lds + bb + i * 512);
  };

  auto rdA = [&](int cb, int mi, int kk) -> s16x8 {
    int ra = wm * 128 + mi * 16 + fr;
    int slot = (kk * 4 + fkslot) ^ (ra & 7);
    return *(const s16x8*)(lds + cb + ra * 64 + slot * 8);
  };
  auto rdB = [&](int cb, int nj, int kk) -> s16x8 {
    int rb = wn * 64 + nj * 16 + fr;
    int slot = (kk * 4 + fkslot) ^ (rb & 7);
    return *(const s16x8*)(lds + cb + 16384 + rb * 64 + slot * 8);
  };

  // ---- prologue ----
  if constexpr (A_F32) {
    issueA(0);
    cvtWriteA(0);                 // compiler inserts the counted vmcnt for areg
    stageB(0, 0);
    issueA(BK2);                  // A(1), consumed at tt=0 step 4 (KT2 >= 2)
  } else {
    stageA_lds(0, 0);
    stageB(0, 0);
  }

  for (int tt = 0; tt < KT2; ++tt) {
    const int cb = (tt & 1) * 32768;

    __builtin_amdgcn_s_barrier();   // (a) all waves done reading buf^1 (tile t-1)
    if constexpr (A_F32) {
      if (tt + 1 < KT2) {
        stageB((tt + 1) & 1, (tt + 1) * BK2);              // 4 gloads (t+1)
        // younger than B(t): A(t+1) 8 + B(t+1) 4 = 12 -> B(t) retired.
        asm volatile("s_waitcnt vmcnt(12)" ::: "memory");
        cvtWriteA((tt + 1) & 1);                           // A(t+1) -> buf^1
        if (tt + 2 < KT2) issueA((tt + 2) * BK2);
      } else {
        asm volatile("s_waitcnt vmcnt(0)" ::: "memory");   // last tile: drain
      }
      asm volatile("s_waitcnt lgkmcnt(0)" ::: "memory");   // ds_writes committed
    } else {
      if (tt + 1 < KT2) {
        stageA_lds((tt + 1) & 1, (tt + 1) * BK2);
        stageB((tt + 1) & 1, (tt + 1) * BK2);
        asm volatile("s_waitcnt vmcnt(8)" ::: "memory");   // tile t's loads retired
      } else {
        asm volatile("s_waitcnt vmcnt(0)" ::: "memory");
      }
    }
    __builtin_amdgcn_s_barrier();   // (b) tile t fully visible

    s16x8 bw[4][2];
#pragma unroll
    for (int nj = 0; nj < 4; ++nj)
#pragma unroll
      for (int kk = 0; kk < 2; ++kk) bw[nj][kk] = rdB(cb, nj, kk);

#pragma unroll
    for (int q = 0; q < 4; ++q) {
      s16x8 af[2][2];
#pragma unroll
      for (int m2 = 0; m2 < 2; ++m2)
#pragma unroll
        for (int kk = 0; kk < 2; ++kk) af[m2][kk] = rdA(cb, q * 2 + m2, kk);
      __builtin_amdgcn_s_setprio(1);
#pragma unroll
      for (int m2 = 0; m2 < 2; ++m2)
#pragma unroll
        for (int nj = 0; nj < 4; ++nj)
#pragma unroll
          for (int kk = 0; kk < 2; ++kk)
            acc[q * 2 + m2][nj] = __builtin_amdgcn_mfma_f32_16x16x32_bf16(
                af[m2][kk], bw[nj][kk], acc[q * 2 + m2][nj], 0, 0, 0);
      __builtin_amdgcn_s_setprio(0);
    }
  }

  // C/D layout: col = lane&15, row = (lane>>4)*4 + r   [verified rounds 1-4]
  const int cr = (lane >> 4) * 4;
  const int cc = lane & 15;
#pragma unroll
  for (int mi = 0; mi < 8; ++mi)
#pragma unroll
    for (int nj = 0; nj < 4; ++nj)
#pragma unroll
      for (int r = 0; r < 4; ++r) {
        size_t row = (size_t)(m0 + wm * 128 + mi * 16 + cr + r);
        size_t col = (size_t)(n0 + wn * 64 + nj * 16 + cc);
        if constexpr (OUT_F32)
          ((float*)Cp)[row * N + col] = acc[mi][nj][r];
        else
          ((unsigned short*)Cp)[row * N + col] = f2b(acc[mi][nj][r]);
      }
}

__global__ __launch_bounds__(512, 2) void proj_gemm8(
    const float* __restrict__ q, const float* __restrict__ k, const float* __restrict__ v,
    const unsigned short* __restrict__ Wqb, const unsigned short* __restrict__ Wkb,
    const unsigned short* __restrict__ Wvb, unsigned short* __restrict__ qh,
    unsigned short* __restrict__ kh, unsigned short* __restrict__ vh) {
  const float* A;
  const unsigned short* W;
  unsigned short* C;
  if (blockIdx.z == 0)      { A = q; W = Wqb; C = qh; }
  else if (blockIdx.z == 1) { A = k; W = Wkb; C = kh; }
  else                      { A = v; W = Wvb; C = vh; }
  gemm8_body<true, false>(A, W, C);
}

__global__ __launch_bounds__(512, 2) void out_gemm8(const unsigned short* __restrict__ attn,
                                                    const unsigned short* __restrict__ Wob,
                                                    float* __restrict__ out) {
  gemm8_body<false, true>(attn, Wob, out);
}

// ---------------- per-token head-axis attention (verified rounds 1-4) --------
__global__ __launch_bounds__(256) void attn_tok(const unsigned short* __restrict__ qh,
                                                const unsigned short* __restrict__ kh,
                                                const unsigned short* __restrict__ vh,
                                                const float* __restrict__ mask,
                                                unsigned short* __restrict__ attn) {
  __shared__ float P[4][16][17];
  __shared__ __align__(16) unsigned short Vs[4][16 * 64];
  const int lane = threadIdx.x & 63;
  const int wid  = threadIdx.x >> 6;
  const size_t tok = (size_t)blockIdx.x * 4 + wid;

  const unsigned short* qp = qh + tok * kD;
  const unsigned short* kp = kh + tok * kD;
  const unsigned short* vp = vh + tok * kD;

  {
    const s16x8* src = (const s16x8*)vp;
    s16x8 a = src[2 * lane], b = src[2 * lane + 1];
    s16x8* dst = (s16x8*)Vs[wid];
    dst[2 * lane] = a;
    dst[2 * lane + 1] = b;
  }

  const int fr = lane & 15;
  const int fk = (lane >> 4) * 8;
  s16x8 a0 = *(const s16x8*)(qp + fr * kDH + fk);
  s16x8 a1 = *(const s16x8*)(qp + fr * kDH + 32 + fk);
  s16x8 b0 = *(const s16x8*)(kp + fr * kDH + fk);
  s16x8 b1 = *(const s16x8*)(kp + fr * kDH + 32 + fk);
  f32x4 s = {0.f, 0.f, 0.f, 0.f};
  s = __builtin_amdgcn_mfma_f32_16x16x32_bf16(a0, b0, s, 0, 0, 0);
  s = __builtin_amdgcn_mfma_f32_16x16x32_bf16(a1, b1, s, 0, 0, 0);

  const int cr = (lane >> 4) * 4;
  const int cc = lane & 15;
  float p[4];
#pragma unroll
  for (int r = 0; r < 4; ++r) {
    float val = s[r] * 0.125f * mask[(cr + r) * kH + cc];
    float mx = val;
#pragma unroll
    for (int d = 1; d < 16; d <<= 1) mx = fmaxf(mx, __shfl_xor(mx, d));
    float e = __expf(val - mx);
    float sum = e;
#pragma unroll
    for (int d = 1; d < 16; d <<= 1) sum += __shfl_xor(sum, d);
    p[r] = e / sum;
  }
#pragma unroll
  for (int r = 0; r < 4; ++r) P[wid][cr + r][cc] = p[r];

  const int h  = lane >> 2;
  const int d0 = (lane & 3) * 16;
  float o[16];
#pragma unroll
  for (int i = 0; i < 16; ++i) o[i] = 0.f;
#pragma unroll
  for (int g = 0; g < 16; ++g) {
    float pg = P[wid][h][g];
    s16x8 v0 = *(const s16x8*)(Vs[wid] + g * kDH + d0);
    s16x8 v1 = *(const s16x8*)(Vs[wid] + g * kDH + d0 + 8);
#pragma unroll
    for (int dd = 0; dd < 8; ++dd) {
      o[dd]     += pg * b2f((unsigned short)v0[dd]);
      o[8 + dd] += pg * b2f((unsigned short)v1[dd]);
    }
  }
  unsigned short* op = attn + tok * kD + h * kDH + d0;
  s16x8 r0, r1;
#pragma unroll
  for (int dd = 0; dd < 8; ++dd) {
    r0[dd] = (short)f2b(o[dd]);
    r1[dd] = (short)f2b(o[dd + 8]);
  }
  *(s16x8*)op = r0;
  *(s16x8*)(op + 8) = r1;
}

// ---------------- fallback (round-1 verified path, fused-cvt GEMM) ----------
constexpr int BM = 128, BN = 128, BK = 32;
constexpr int LDSP = BK + 8;
__device__ __forceinline__ void cvt16_store(const float* __restrict__ g, short* __restrict__ l) {
  const f32x4* s4 = (const f32x4*)g;
  f32x4 f0 = s4[0], f1 = s4[1], f2 = s4[2], f3 = s4[3];
  s16x8 o0, o1;
#pragma unroll
  for (int i = 0; i < 4; ++i) {
    o0[i]     = (short)f2b(f0[i]);
    o0[4 + i] = (short)f2b(f1[i]);
    o1[i]     = (short)f2b(f2[i]);
    o1[4 + i] = (short)f2b(f3[i]);
  }
  *(s16x8*)l = o0;
  *(s16x8*)(l + 8) = o1;
}

template <bool A_BF16, bool OUT_F32>
__device__ __forceinline__ void gemm_body_cvt(const void* __restrict__ Ap,
                                              const float* __restrict__ Wp,
                                              void* __restrict__ Cp) {
  constexpr int N = kD, K = kD;
  __shared__ short As[BM * LDSP];
  __shared__ short Bs[BN * LDSP];
  const int t  = threadIdx.x;
  const int m0 = blockIdx.y * BM;
  const int n0 = blockIdx.x * BN;
  const int srow = t >> 1;
  const int scol = (t & 1) * 16;
  const int lane = t & 63;
  const int wid  = t >> 6;
  const int wm   = (wid >> 1) * 64;
  const int wn   = (wid & 1) * 64;
  const int fr   = lane & 15;
  const int fk   = (lane >> 4) * 8;

  f32x4 acc[4][4];
#pragma unroll
  for (int i = 0; i < 4; ++i)
#pragma unroll
    for (int j = 0; j < 4; ++j) acc[i][j] = (f32x4){0.f, 0.f, 0.f, 0.f};

  for (int k0 = 0; k0 < K; k0 += BK) {
    if constexpr (A_BF16) {
      const unsigned short* Ab = (const unsigned short*)Ap;
      const s16x8* src = (const s16x8*)(Ab + (size_t)(m0 + srow) * K + k0 + scol);
      s16x8 v0 = src[0], v1 = src[1];
      *(s16x8*)(As + srow * LDSP + scol) = v0;
      *(s16x8*)(As + srow * LDSP + scol + 8) = v1;
    } else {
      cvt16_store((const float*)Ap + (size_t)(m0 + srow) * K + k0 + scol,
                  As + srow * LDSP + scol);
    }
    cvt16_store(Wp + (size_t)(n0 + srow) * K + k0 + scol, Bs + srow * LDSP + scol);
    __syncthreads();
    s16x8 af[4], bw[4];
#pragma unroll
    for (int i = 0; i < 4; ++i)
      af[i] = *(const s16x8*)(As + (wm + i * 16 + fr) * LDSP + fk);
#pragma unroll
    for (int j = 0; j < 4; ++j)
      bw[j] = *(const s16x8*)(Bs + (wn + j * 16 + fr) * LDSP + fk);
#pragma unroll
    for (int i = 0; i < 4; ++i)
#pragma unroll
      for (int j = 0; j < 4; ++j)
        acc[i][j] = __builtin_amdgcn_mfma_f32_16x16x32_bf16(af[i], bw[j], acc[i][j], 0, 0, 0);
    __syncthreads();
  }
  const int cr = (lane >> 4) * 4;
  const int cc = lane & 15;
#pragma unroll
  for (int i = 0; i < 4; ++i)
#pragma unroll
    for (int j = 0; j < 4; ++j)
#pragma unroll
      for (int r = 0; r < 4; ++r) {
        size_t row = (size_t)(m0 + wm + i * 16 + cr + r);
        size_t col = (size_t)(n0 + wn + j * 16 + cc);
        if constexpr (OUT_F32)
          ((float*)Cp)[row * N + col] = acc[i][j][r];
        else
          ((unsigned short*)Cp)[row * N + col] = f2b(acc[i][j][r]);
      }
}

__global__ __launch_bounds__(256) void proj_gemm_cvt(
    const float* __restrict__ q, const float* __restrict__ k, const float* __restrict__ v,
    const float* __restrict__ Wq, const float* __restrict__ Wk, const float* __restrict__ Wv,
    unsigned short* __restrict__ qh, unsigned short* __restrict__ kh,
    unsigned short* __restrict__ vh) {
  const float* A; const float* W; unsigned short* C;
  if (blockIdx.z == 0)      { A = q; W = Wq; C = qh; }
  else if (blockIdx.z == 1) { A = k; W = Wk; C = kh; }
  else                      { A = v; W = Wv; C = vh; }
  gemm_body_cvt<false, false>(A, W, C);
}

__global__ __launch_bounds__(256) void out_gemm_cvt(const unsigned short* __restrict__ attn,
                                                    const float* __restrict__ Wo,
                                                    float* __restrict__ out) {
  gemm_body_cvt<true, true>(attn, Wo, out);
}

}  // namespace

extern "C" void kernel_launch(void* const* d_in, const int* in_sizes, int n_in,
                              void* d_out, int out_size, void* d_ws, size_t ws_size,
                              hipStream_t stream) {
  (void)in_sizes; (void)n_in; (void)out_size;
  const float* q    = (const float*)d_in[0];
  const float* k    = (const float*)d_in[1];
  const float* v    = (const float*)d_in[2];
  const float* mask = (const float*)d_in[3];
  const float* Wq   = (const float*)d_in[4];
  const float* Wk   = (const float*)d_in[5];
  const float* Wv   = (const float*)d_in[6];
  const float* Wo   = (const float*)d_in[7];

  const size_t need = (3 * PER + 4 * WSZ) * sizeof(unsigned short);  // ~109 MB
  if (ws_size >= need) {
    unsigned short* Wqb = (unsigned short*)d_ws;   // ws: Wq Wk Wv Wo | qh kh vh
    unsigned short* Wkb = Wqb + WSZ;
    unsigned short* Wvb = Wkb + WSZ;
    unsigned short* Wob = Wvb + WSZ;
    unsigned short* qh  = Wob + WSZ;
    unsigned short* kh  = qh + PER;
    unsigned short* vh  = kh + PER;
    // at aliases qh: attn wave reads token t's q-row before writing its attn
    // row (same wave, read-before-write, rows disjoint across tokens).
    unsigned short* at  = qh;

    cvt_w<<<256, 256, 0, stream>>>(Wq, Wk, Wv, Wo, Wqb);
    proj_gemm8<<<dim3(kD / BN2, kM / BM2, 3), 512, 0, stream>>>(q, k, v, Wqb, Wkb, Wvb,
                                                                qh, kh, vh);
    attn_tok<<<dim3(kM / 4), 256, 0, stream>>>(qh, kh, vh, mask, at);
    out_gemm8<<<dim3(kD / BN2, kM / BM2), 512, 0, stream>>>(at, Wob, (float*)d_out);
  } else {
    // round-1 verified fallback (fused-convert GEMMs)
    unsigned short* qh = (unsigned short*)d_ws;
    unsigned short* kh = qh + PER;
    unsigned short* vh = kh + PER;
    unsigned short* at = (ws_size >= 4 * PER * sizeof(unsigned short)) ? (vh + PER) : qh;
    proj_gemm_cvt<<<dim3(kD / BN, kM / BM, 3), 256, 0, stream>>>(q, k, v, Wq, Wk, Wv,
                                                                 qh, kh, vh);
    attn_tok<<<dim3(kM / 4), 256, 0, stream>>>(qh, kh, vh, mask, at);
    out_gemm_cvt<<<dim3(kD / BN, kM / BM), 256, 0, stream>>>(at, Wo, (float*)d_out);
  }
}